// Round 18
// baseline (74.641 us; speedup 1.0000x reference)
//
#include <hip/hip_runtime.h>
#include <hip/hip_bf16.h>

// MultiHeadAttention: x(16,512,256) f32; mask(1,16,512,512) bool; adj(1,16,512,512) f32;
// Wq/Wk/Wv (256,256) f32.  out = softmax(QK^T/sqrt(64) + adj, mask) @ V + x, f32.
// R17: register-batched loads. R16 showed 52 VGPR forces dribbled loads (~10
// exposed L3 waits/tile). launch_bounds(512,2) -> cap 128 (cap=256/w model).
// Schedule: V(t) issued BEFORE QK^T (hides under QK+softmax); K(t+1) prefetched
// after QK^T(t) (hides under softmax+PV). ~123 VGPR, 2 exposed waits/wave.
// Occupancy unchanged (grid-pinned 2 blocks/CU); barriers stay at 1 (R16).

#define NB 16
#define NA 512
#define HID 256
#define NHEAD 8
#define DH 32
#define INV_TP 0.125f  // 1/sqrt(2*32)
#define ADJ_LD 520     // 512 cols + 8 pad (f32)

typedef __attribute__((ext_vector_type(8))) short short8;   // 8 bf16 MFMA frag
typedef __attribute__((ext_vector_type(4))) float floatx4;  // MFMA acc

__device__ __forceinline__ unsigned short f2bf(float f) {
  unsigned int u = __builtin_bit_cast(unsigned int, f);
  u += 0x7fffu + ((u >> 16) & 1u);  // round-to-nearest-even
  return (unsigned short)(u >> 16);
}

__device__ __forceinline__ floatx4 mfma16(short8 a, short8 b, floatx4 c) {
  return __builtin_amdgcn_mfma_f32_16x16x32_bf16(a, b, c, 0, 0, 0);
}

__device__ __forceinline__ short8 ld8f32_bf16(const float* __restrict__ p) {
  float4 a = *(const float4*)p;
  float4 b = *(const float4*)(p + 4);
  short8 r;
  r[0] = (short)f2bf(a.x); r[1] = (short)f2bf(a.y);
  r[2] = (short)f2bf(a.z); r[3] = (short)f2bf(a.w);
  r[4] = (short)f2bf(b.x); r[5] = (short)f2bf(b.y);
  r[6] = (short)f2bf(b.z); r[7] = (short)f2bf(b.w);
  return r;
}

// Streaming f32->bf16 for X (2M elems) and Wq/Wk/Wv (64K each). Memory-bound.
__global__ __launch_bounds__(256) void cvt_bf16(
    const float* __restrict__ X, const float* __restrict__ Wq,
    const float* __restrict__ Wk, const float* __restrict__ Wv,
    unsigned short* __restrict__ Xbf, unsigned short* __restrict__ Wbf) {
  const int tid = blockIdx.x * blockDim.x + threadIdx.x;
  const int stride = gridDim.x * blockDim.x;
  for (int i = tid; i < (NB * NA * HID) / 4; i += stride) {
    float4 v = ((const float4*)X)[i];
    ushort4 w;
    w.x = f2bf(v.x); w.y = f2bf(v.y); w.z = f2bf(v.z); w.w = f2bf(v.w);
    ((ushort4*)Xbf)[i] = w;
  }
  for (int i = tid; i < (HID * HID) / 4; i += stride) {
    float4 v = ((const float4*)Wq)[i];
    ushort4 w;
    w.x = f2bf(v.x); w.y = f2bf(v.y); w.z = f2bf(v.z); w.w = f2bf(v.w);
    ((ushort4*)Wbf)[i] = w;
    v = ((const float4*)Wk)[i];
    w.x = f2bf(v.x); w.y = f2bf(v.y); w.z = f2bf(v.z); w.w = f2bf(v.w);
    ((ushort4*)(Wbf + HID * HID))[i] = w;
    v = ((const float4*)Wv)[i];
    w.x = f2bf(v.x); w.y = f2bf(v.y); w.z = f2bf(v.z); w.w = f2bf(v.w);
    ((ushort4*)(Wbf + 2 * HID * HID))[i] = w;
  }
}

// Pure-bf16 projection: Y[m][c] = sum_k Xbf[m][k] * Wbf[c][k].
// Q,K stored [b][h][n][d]; V stored TRANSPOSED [b][h][d][n].
__global__ __launch_bounds__(256) void qkv_proj_bf(
    const unsigned short* __restrict__ Xbf, const unsigned short* __restrict__ Wbf,
    unsigned short* __restrict__ Y) {
  const unsigned short* W = Wbf + (size_t)blockIdx.y * (HID * HID);
  unsigned short* Yo = Y + (size_t)blockIdx.y * (NB * NHEAD * NA * DH);
  const int wave = threadIdx.x >> 6, lane = threadIdx.x & 63;
  const int lr = lane & 15, lh = lane >> 4;
  const int m0 = blockIdx.x * 32;
  const int cb = wave * 64;
  const floatx4 z = {0.f, 0.f, 0.f, 0.f};
  floatx4 acc[2][4];
#pragma unroll
  for (int i = 0; i < 2; i++)
#pragma unroll
    for (int j = 0; j < 4; j++) acc[i][j] = z;

  for (int kb = 0; kb < HID; kb += 32) {
    short8 a[2], bw[4];
#pragma unroll
    for (int rt = 0; rt < 2; rt++)
      a[rt] = *(const short8*)&Xbf[(size_t)(m0 + rt * 16 + lr) * HID + kb + lh * 8];
#pragma unroll
    for (int ci = 0; ci < 4; ci++)
      bw[ci] = *(const short8*)&W[(size_t)(cb + ci * 16 + lr) * HID + kb + lh * 8];
#pragma unroll
    for (int rt = 0; rt < 2; rt++)
#pragma unroll
      for (int ci = 0; ci < 4; ci++)
        acc[rt][ci] = mfma16(a[rt], bw[ci], acc[rt][ci]);
  }
  if (blockIdx.y == 2) {
    // V: [b][h][d][n], 4 consecutive n (rows m..m+3) packed per store.
#pragma unroll
    for (int rt = 0; rt < 2; rt++)
#pragma unroll
      for (int ci = 0; ci < 4; ci++) {
        int m = m0 + rt * 16 + lh * 4;       // rows m..m+3 (same batch: 32|512)
        int c = cb + ci * 16 + lr;
        int bb = m >> 9, n0 = m & 511, hh = c >> 5, dd = c & 31;
        ushort4 w;
        w.x = f2bf(acc[rt][ci][0]);
        w.y = f2bf(acc[rt][ci][1]);
        w.z = f2bf(acc[rt][ci][2]);
        w.w = f2bf(acc[rt][ci][3]);
        *(ushort4*)&Yo[((size_t)(bb * NHEAD + hh) * DH + dd) * NA + n0] = w;
      }
  } else {
#pragma unroll
    for (int rt = 0; rt < 2; rt++)
#pragma unroll
      for (int ci = 0; ci < 4; ci++)
#pragma unroll
        for (int r = 0; r < 4; r++) {
          int m = m0 + rt * 16 + lh * 4 + r;   // D layout: row=(l>>4)*4+reg
          int c = cb + ci * 16 + lr;           //           col=l&15
          int bb = m >> 9, n = m & 511, hh = c >> 5, dd = c & 31;
          Yo[((size_t)(bb * NHEAD + hh) * NA + n) * DH + dd] = f2bf(acc[rt][ci][r]);
        }
  }
}

// Fallback projection: inline f32->bf16. Used only if ws too small.
__global__ __launch_bounds__(256) void qkv_proj(
    const float* __restrict__ X, const float* __restrict__ Wq,
    const float* __restrict__ Wk, const float* __restrict__ Wv,
    unsigned short* __restrict__ Y) {
  const float* W = (blockIdx.y == 0) ? Wq : (blockIdx.y == 1) ? Wk : Wv;
  unsigned short* Yo = Y + (size_t)blockIdx.y * (NB * NHEAD * NA * DH);
  const int wave = threadIdx.x >> 6, lane = threadIdx.x & 63;
  const int lr = lane & 15, lh = lane >> 4;
  const int m0 = blockIdx.x * 32;
  const int cb = wave * 64;
  const floatx4 z = {0.f, 0.f, 0.f, 0.f};
  floatx4 acc[2][4];
#pragma unroll
  for (int i = 0; i < 2; i++)
#pragma unroll
    for (int j = 0; j < 4; j++) acc[i][j] = z;

  for (int kb = 0; kb < HID; kb += 32) {
    short8 a[2], bw[4];
#pragma unroll
    for (int rt = 0; rt < 2; rt++)
      a[rt] = ld8f32_bf16(X + (size_t)(m0 + rt * 16 + lr) * HID + kb + lh * 8);
#pragma unroll
    for (int ci = 0; ci < 4; ci++)
      bw[ci] = ld8f32_bf16(W + (size_t)(cb + ci * 16 + lr) * HID + kb + lh * 8);
#pragma unroll
    for (int rt = 0; rt < 2; rt++)
#pragma unroll
      for (int ci = 0; ci < 4; ci++)
        acc[rt][ci] = mfma16(a[rt], bw[ci], acc[rt][ci]);
  }
  if (blockIdx.y == 2) {
#pragma unroll
    for (int rt = 0; rt < 2; rt++)
#pragma unroll
      for (int ci = 0; ci < 4; ci++) {
        int m = m0 + rt * 16 + lh * 4;
        int c = cb + ci * 16 + lr;
        int bb = m >> 9, n0 = m & 511, hh = c >> 5, dd = c & 31;
        ushort4 w;
        w.x = f2bf(acc[rt][ci][0]);
        w.y = f2bf(acc[rt][ci][1]);
        w.z = f2bf(acc[rt][ci][2]);
        w.w = f2bf(acc[rt][ci][3]);
        *(ushort4*)&Yo[((size_t)(bb * NHEAD + hh) * DH + dd) * NA + n0] = w;
      }
  } else {
#pragma unroll
    for (int rt = 0; rt < 2; rt++)
#pragma unroll
      for (int ci = 0; ci < 4; ci++)
#pragma unroll
        for (int r = 0; r < 4; r++) {
          int m = m0 + rt * 16 + lh * 4 + r;
          int c = cb + ci * 16 + lr;
          int bb = m >> 9, n = m & 511, hh = c >> 5, dd = c & 31;
          Yo[((size_t)(bb * NHEAD + hh) * NA + n) * DH + dd] = f2bf(acc[rt][ci][r]);
        }
  }
}

// grid: (32 q-blocks of 16 rows, 16 batch) = 512 blocks (2/CU exact), 512 thr.
// Wave h = head h, all 512 keys (4 tiles of 128, online softmax).
// Bias staged once (1 barrier). Load-batched: V(t) before QK, K(t+1) after QK.
__global__ __launch_bounds__(512, 2) void attn_fused(
    const unsigned short* __restrict__ Qw, const unsigned short* __restrict__ Kw,
    const unsigned short* __restrict__ Vtg, const float* __restrict__ X,
    const unsigned char* __restrict__ maskB, const int* __restrict__ maskI,
    const float* __restrict__ adj, float* __restrict__ out) {
  __shared__ float adj_lds[16][ADJ_LD];  // 33,280 B
  const int qb = blockIdx.x, b = blockIdx.y;
  const int t = threadIdx.x;
  const int h = t >> 6, lane = t & 63, lr = lane & 15, lh = lane >> 4;
  const int q0 = qb * 16;
  const size_t bh = (size_t)(b * NHEAD + h) * NA * DH;
  const unsigned short* Kg = Kw + bh;
  const unsigned short* Vg = Vtg + bh;  // [d][n]: d*NA + n

  // Q fragment + K(0) fragments issued first (independent of staging)
  short8 qf = *(const short8*)&Qw[bh + (size_t)(q0 + lr) * DH + lh * 8];
  short8 kf[8];
#pragma unroll
  for (int kt = 0; kt < 8; kt++)
    kf[kt] = *(const short8*)&Kg[(size_t)(kt * 16 + lr) * DH + lh * 8];

  // mask dtype detect (wave-level over first 512 words; wave-uniform result).
  const unsigned int* mu = (const unsigned int*)maskB;
  unsigned int cnt = 0;
#pragma unroll
  for (int j = 0; j < 8; j++) cnt += (mu[lane + j * 64] != 0u) ? 1u : 0u;
#pragma unroll
  for (int off = 32; off > 0; off >>= 1) cnt += __shfl_xor(cnt, off);
  const bool mBytes = (cnt > 368u);

  // stage the full 16x512 bias block (mask merged: masked -> -1e30).
#pragma unroll
  for (int j = 0; j < 4; j++) {
    const int slot = t + j * 512;
    const int srow = slot >> 7;            // 128 float4 per row
    const int sc4 = (slot & 127) * 4;
    const size_t soff = ((size_t)b * NA + q0 + srow) * NA + sc4;
    float4 av = *(const float4*)&adj[soff];
    if (mBytes) {
      uchar4 mb = *(const uchar4*)&maskB[soff];
      if (mb.x) av.x = -1e30f;
      if (mb.y) av.y = -1e30f;
      if (mb.z) av.z = -1e30f;
      if (mb.w) av.w = -1e30f;
    } else {
      int4 mi = *(const int4*)&maskI[soff];
      if (mi.x) av.x = -1e30f;
      if (mi.y) av.y = -1e30f;
      if (mi.z) av.z = -1e30f;
      if (mi.w) av.w = -1e30f;
    }
    *(float4*)&adj_lds[srow][sc4] = av;
  }
  __syncthreads();  // the ONLY barrier

  const floatx4 z = {0.f, 0.f, 0.f, 0.f};
  float m_run = -3.0e38f, l_run = 0.f;  // state for q = q0 + lr (S^T layout)
  floatx4 o0 = z, o1 = z;               // rows q0 + lh*4 + r (C/D layout)

#pragma unroll 1
  for (int tile = 0; tile < 4; ++tile) {
    const int keyoff = tile * 128;

    // (1) issue V(tile) loads FIRST — independent of softmax; latency hides
    // under QK^T + softmax. 8 uint2-pairs = 32 VGPRs.
    uint2 v0a[4], v0b[4], v1a[4], v1b[4];
#pragma unroll
    for (int kc = 0; kc < 4; kc++) {
      const int kbase = keyoff + kc * 32 + lh * 4;
      v0a[kc] = *(const uint2*)&Vg[(size_t)lr * NA + kbase];
      v0b[kc] = *(const uint2*)&Vg[(size_t)lr * NA + kbase + 16];
      v1a[kc] = *(const uint2*)&Vg[(size_t)(16 + lr) * NA + kbase];
      v1b[kc] = *(const uint2*)&Vg[(size_t)(16 + lr) * NA + kbase + 16];
    }

    // (2) S^T = K * Q^T from the preloaded K buffer
    floatx4 s[8];
#pragma unroll
    for (int kt = 0; kt < 8; kt++) s[kt] = z;
#pragma unroll
    for (int kt = 0; kt < 8; kt++) s[kt] = mfma16(kf[kt], qf, s[kt]);

    // (3) prefetch K(tile+1) — latency hides under softmax + PV
    if (tile < 3) {
      const int nko = keyoff + 128;
#pragma unroll
      for (int kt = 0; kt < 8; kt++)
        kf[kt] = *(const short8*)&Kg[(size_t)(nko + kt * 16 + lr) * DH + lh * 8];
    }

    // (4) bias + softmax (V and K-next in flight underneath)
    float pmax = -3.0e38f;
#pragma unroll
    for (int kt = 0; kt < 8; kt++) {
      float4 av = *(const float4*)&adj_lds[lr][keyoff + kt * 16 + lh * 4];
      float v0 = s[kt][0] * INV_TP + av.x;
      float v1 = s[kt][1] * INV_TP + av.y;
      float v2 = s[kt][2] * INV_TP + av.z;
      float v3 = s[kt][3] * INV_TP + av.w;
      s[kt][0] = v0; s[kt][1] = v1; s[kt][2] = v2; s[kt][3] = v3;
      pmax = fmaxf(pmax, fmaxf(fmaxf(v0, v1), fmaxf(v2, v3)));
    }
    // row q lives in lanes {lr, lr+16, lr+32, lr+48}
    pmax = fmaxf(pmax, __shfl_xor(pmax, 16));
    pmax = fmaxf(pmax, __shfl_xor(pmax, 32));

    const float mnew = fmaxf(m_run, pmax);
    if (tile) {  // tile 0: o/l are zero, skip rescale
      const float corr = __expf(m_run - mnew);
      l_run *= corr;
#pragma unroll
      for (int r = 0; r < 4; r++) {
        float c = __shfl(corr, lh * 4 + r, 64);
        o0[r] *= c;
        o1[r] *= c;
      }
    }
    m_run = mnew;

    float sum = 0.f;
#pragma unroll
    for (int kt = 0; kt < 8; kt++) {
      float e0 = __expf(s[kt][0] - mnew);
      float e1 = __expf(s[kt][1] - mnew);
      float e2 = __expf(s[kt][2] - mnew);
      float e3 = __expf(s[kt][3] - mnew);
      s[kt][0] = e0; s[kt][1] = e1; s[kt][2] = e2; s[kt][3] = e3;
      sum += (e0 + e1) + (e2 + e3);
    }
    sum += __shfl_xor(sum, 16);
    sum += __shfl_xor(sum, 32);
    l_run += sum;

    // (5) PV, relabeled K-dim: slot lh*8+j <-> key keyoff+32kc+(j<4?lh*4+j:16+lh*4+j-4)
#pragma unroll
    for (int kc = 0; kc < 4; kc++) {
      union { short8 s8; unsigned int u[4]; } aa;
      aa.u[0] = (unsigned int)f2bf(s[2 * kc][0]) |
                ((unsigned int)f2bf(s[2 * kc][1]) << 16);
      aa.u[1] = (unsigned int)f2bf(s[2 * kc][2]) |
                ((unsigned int)f2bf(s[2 * kc][3]) << 16);
      aa.u[2] = (unsigned int)f2bf(s[2 * kc + 1][0]) |
                ((unsigned int)f2bf(s[2 * kc + 1][1]) << 16);
      aa.u[3] = (unsigned int)f2bf(s[2 * kc + 1][2]) |
                ((unsigned int)f2bf(s[2 * kc + 1][3]) << 16);
      union { short8 s8; uint2 u2[2]; } v0f, v1f;
      v0f.u2[0] = v0a[kc];
      v0f.u2[1] = v0b[kc];
      v1f.u2[0] = v1a[kc];
      v1f.u2[1] = v1b[kc];
      o0 = mfma16(aa.s8, v0f.s8, o0);
      o1 = mfma16(aa.s8, v1f.s8, o1);
    }
  }

  const float inv = 1.0f / l_run;  // for q = q0 + lr
#pragma unroll
  for (int r = 0; r < 4; r++) {
    float iv = __shfl(inv, lh * 4 + r, 64);  // row q0+lh*4+r's normalizer
    size_t idx = ((size_t)b * NA + (q0 + lh * 4 + r)) * HID + h * DH + lr;
    out[idx] = o0[r] * iv + X[idx];
    out[idx + 16] = o1[r] * iv + X[idx + 16];
  }
}

extern "C" void kernel_launch(void* const* d_in, const int* in_sizes, int n_in,
                              void* d_out, int out_size, void* d_ws, size_t ws_size,
                              hipStream_t stream) {
  const float* x = (const float*)d_in[0];
  const void* mask = d_in[1];
  const float* adj = (const float*)d_in[2];
  const float* Wq = (const float*)d_in[3];
  const float* Wk = (const float*)d_in[4];
  const float* Wv = (const float*)d_in[5];
  float* out = (float*)d_out;

  char* ws = (char*)d_ws;
  const size_t MB = 1048576;
  const size_t NEED = 4 * MB + 512 * 1024 + 3 * 4 * MB;  // Xbf + Wbf + QKV = 16.5MB

  unsigned short *Qw, *Kw, *Vw;
  if (ws_size >= NEED) {
    unsigned short* Xbf = (unsigned short*)ws;                   // 4 MB
    unsigned short* Wbf = (unsigned short*)(ws + 4 * MB);        // 384 KB (+pad)
    Qw = (unsigned short*)(ws + 4 * MB + 512 * 1024);            // 4 MB
    Kw = (unsigned short*)(ws + 8 * MB + 512 * 1024);            // 4 MB
    Vw = (unsigned short*)(ws + 12 * MB + 512 * 1024);           // 4 MB (transposed)
    cvt_bf16<<<1024, 256, 0, stream>>>(x, Wq, Wk, Wv, Xbf, Wbf);
    qkv_proj_bf<<<dim3(256, 3), 256, 0, stream>>>(Xbf, Wbf, Qw);
  } else {
    Qw = (unsigned short*)(ws + 4096);
    Kw = (unsigned short*)(ws + 4096 + 4 * MB);
    Vw = (unsigned short*)(ws + 4096 + 8 * MB);
    qkv_proj<<<dim3(256, 3), 256, 0, stream>>>(x, Wq, Wk, Wv, Qw);
  }
  attn_fused<<<dim3(32, NB), 512, 0, stream>>>(
      Qw, Kw, Vw, x, (const unsigned char*)mask, (const int*)mask, adj, out);
}

// Round 21
// 61.476 us; speedup vs baseline: 1.2141x; 1.2141x over previous
//
#include <hip/hip_runtime.h>
#include <hip/hip_bf16.h>

// MultiHeadAttention: x(16,512,256) f32; mask(1,16,512,512) bool; adj(1,16,512,512) f32;
// Wq/Wk/Wv (256,256) f32.  out = softmax(QK^T/sqrt(64) + adj, mask) @ V + x, f32.
// R20: bisect of R18's NaN. KEEP V key-permute (algebra-verified: vperm32 maps
// write-side key g -> position so PV B-frag slots are 16B-contiguous; halves V
// txn stream). REVERT v_cvt_pk_bf16_f32 inline asm -> R17's validated f2bf
// packing (the only bit-level mechanism that could inject NaN).
// Everything else identical to R17/R18 lineage.

#define NB 16
#define NA 512
#define HID 256
#define NHEAD 8
#define DH 32
#define INV_TP 0.125f  // 1/sqrt(2*32)
#define ADJ_LD 520     // 512 cols + 8 pad (f32)

typedef __attribute__((ext_vector_type(8))) short short8;   // 8 bf16 MFMA frag
typedef __attribute__((ext_vector_type(4))) float floatx4;  // MFMA acc

__device__ __forceinline__ unsigned short f2bf(float f) {
  unsigned int u = __builtin_bit_cast(unsigned int, f);
  u += 0x7fffu + ((u >> 16) & 1u);  // round-to-nearest-even
  return (unsigned short)(u >> 16);
}

__device__ __forceinline__ floatx4 mfma16(short8 a, short8 b, floatx4 c) {
  return __builtin_amdgcn_mfma_f32_16x16x32_bf16(a, b, c, 0, 0, 0);
}

__device__ __forceinline__ short8 ld8f32_bf16(const float* __restrict__ p) {
  float4 a = *(const float4*)p;
  float4 b = *(const float4*)(p + 4);
  short8 r;
  r[0] = (short)f2bf(a.x); r[1] = (short)f2bf(a.y);
  r[2] = (short)f2bf(a.z); r[3] = (short)f2bf(a.w);
  r[4] = (short)f2bf(b.x); r[5] = (short)f2bf(b.y);
  r[6] = (short)f2bf(b.z); r[7] = (short)f2bf(b.w);
  return r;
}

// V key permutation within each 32-key group: old g -> new position.
// Makes PV B-frag keys contiguous per (kc, lh): new = lh*8 + (0..7).
__device__ __forceinline__ int vperm32(int g) {
  return (((g & 15) >> 2) << 3) + (g & 3) + (((g >> 4) & 1) << 2);
}

// Streaming f32->bf16 for X (2M elems) and Wq/Wk/Wv (64K each). Memory-bound.
__global__ __launch_bounds__(256) void cvt_bf16(
    const float* __restrict__ X, const float* __restrict__ Wq,
    const float* __restrict__ Wk, const float* __restrict__ Wv,
    unsigned short* __restrict__ Xbf, unsigned short* __restrict__ Wbf) {
  const int tid = blockIdx.x * blockDim.x + threadIdx.x;
  const int stride = gridDim.x * blockDim.x;
  for (int i = tid; i < (NB * NA * HID) / 4; i += stride) {
    float4 v = ((const float4*)X)[i];
    ushort4 w;
    w.x = f2bf(v.x); w.y = f2bf(v.y); w.z = f2bf(v.z); w.w = f2bf(v.w);
    ((ushort4*)Xbf)[i] = w;
  }
  for (int i = tid; i < (HID * HID) / 4; i += stride) {
    float4 v = ((const float4*)Wq)[i];
    ushort4 w;
    w.x = f2bf(v.x); w.y = f2bf(v.y); w.z = f2bf(v.z); w.w = f2bf(v.w);
    ((ushort4*)Wbf)[i] = w;
    v = ((const float4*)Wk)[i];
    w.x = f2bf(v.x); w.y = f2bf(v.y); w.z = f2bf(v.z); w.w = f2bf(v.w);
    ((ushort4*)(Wbf + HID * HID))[i] = w;
    v = ((const float4*)Wv)[i];
    w.x = f2bf(v.x); w.y = f2bf(v.y); w.z = f2bf(v.z); w.w = f2bf(v.w);
    ((ushort4*)(Wbf + 2 * HID * HID))[i] = w;
  }
}

// Pure-bf16 projection: Y[m][c] = sum_k Xbf[m][k] * Wbf[c][k].
// Q,K stored [b][h][n][d]; V stored TRANSPOSED [b][h][d][n'] with n' = key-
// permuted within 32-groups (vperm32) so attn PV loads are 16B-contiguous.
__global__ __launch_bounds__(256) void qkv_proj_bf(
    const unsigned short* __restrict__ Xbf, const unsigned short* __restrict__ Wbf,
    unsigned short* __restrict__ Y) {
  const unsigned short* W = Wbf + (size_t)blockIdx.y * (HID * HID);
  unsigned short* Yo = Y + (size_t)blockIdx.y * (NB * NHEAD * NA * DH);
  const int wave = threadIdx.x >> 6, lane = threadIdx.x & 63;
  const int lr = lane & 15, lh = lane >> 4;
  const int m0 = blockIdx.x * 32;
  const int cb = wave * 64;
  const floatx4 z = {0.f, 0.f, 0.f, 0.f};
  floatx4 acc[2][4];
#pragma unroll
  for (int i = 0; i < 2; i++)
#pragma unroll
    for (int j = 0; j < 4; j++) acc[i][j] = z;

  for (int kb = 0; kb < HID; kb += 32) {
    short8 a[2], bw[4];
#pragma unroll
    for (int rt = 0; rt < 2; rt++)
      a[rt] = *(const short8*)&Xbf[(size_t)(m0 + rt * 16 + lr) * HID + kb + lh * 8];
#pragma unroll
    for (int ci = 0; ci < 4; ci++)
      bw[ci] = *(const short8*)&W[(size_t)(cb + ci * 16 + lr) * HID + kb + lh * 8];
#pragma unroll
    for (int rt = 0; rt < 2; rt++)
#pragma unroll
      for (int ci = 0; ci < 4; ci++)
        acc[rt][ci] = mfma16(a[rt], bw[ci], acc[rt][ci]);
  }
  if (blockIdx.y == 2) {
    // V: [b][h][d][n'], 4 consecutive keys -> contiguous permuted positions.
#pragma unroll
    for (int rt = 0; rt < 2; rt++)
#pragma unroll
      for (int ci = 0; ci < 4; ci++) {
        int m = m0 + rt * 16 + lh * 4;       // keys m..m+3 (same batch: 32|512)
        int c = cb + ci * 16 + lr;
        int bb = m >> 9, n0 = m & 511, hh = c >> 5, dd = c & 31;
        int np = (n0 & ~31) | vperm32(n0 & 31);  // 4-aligned, stays contiguous
        ushort4 w;
        w.x = f2bf(acc[rt][ci][0]);
        w.y = f2bf(acc[rt][ci][1]);
        w.z = f2bf(acc[rt][ci][2]);
        w.w = f2bf(acc[rt][ci][3]);
        *(ushort4*)&Yo[((size_t)(bb * NHEAD + hh) * DH + dd) * NA + np] = w;
      }
  } else {
#pragma unroll
    for (int rt = 0; rt < 2; rt++)
#pragma unroll
      for (int ci = 0; ci < 4; ci++)
#pragma unroll
        for (int r = 0; r < 4; r++) {
          int m = m0 + rt * 16 + lh * 4 + r;   // D layout: row=(l>>4)*4+reg
          int c = cb + ci * 16 + lr;           //           col=l&15
          int bb = m >> 9, n = m & 511, hh = c >> 5, dd = c & 31;
          Yo[((size_t)(bb * NHEAD + hh) * NA + n) * DH + dd] = f2bf(acc[rt][ci][r]);
        }
  }
}

// Fallback projection: inline f32->bf16. Used only if ws too small.
__global__ __launch_bounds__(256) void qkv_proj(
    const float* __restrict__ X, const float* __restrict__ Wq,
    const float* __restrict__ Wk, const float* __restrict__ Wv,
    unsigned short* __restrict__ Y) {
  const float* W = (blockIdx.y == 0) ? Wq : (blockIdx.y == 1) ? Wk : Wv;
  unsigned short* Yo = Y + (size_t)blockIdx.y * (NB * NHEAD * NA * DH);
  const int wave = threadIdx.x >> 6, lane = threadIdx.x & 63;
  const int lr = lane & 15, lh = lane >> 4;
  const int m0 = blockIdx.x * 32;
  const int cb = wave * 64;
  const floatx4 z = {0.f, 0.f, 0.f, 0.f};
  floatx4 acc[2][4];
#pragma unroll
  for (int i = 0; i < 2; i++)
#pragma unroll
    for (int j = 0; j < 4; j++) acc[i][j] = z;

  for (int kb = 0; kb < HID; kb += 32) {
    short8 a[2], bw[4];
#pragma unroll
    for (int rt = 0; rt < 2; rt++)
      a[rt] = ld8f32_bf16(X + (size_t)(m0 + rt * 16 + lr) * HID + kb + lh * 8);
#pragma unroll
    for (int ci = 0; ci < 4; ci++)
      bw[ci] = ld8f32_bf16(W + (size_t)(cb + ci * 16 + lr) * HID + kb + lh * 8);
#pragma unroll
    for (int rt = 0; rt < 2; rt++)
#pragma unroll
      for (int ci = 0; ci < 4; ci++)
        acc[rt][ci] = mfma16(a[rt], bw[ci], acc[rt][ci]);
  }
  if (blockIdx.y == 2) {
#pragma unroll
    for (int rt = 0; rt < 2; rt++)
#pragma unroll
      for (int ci = 0; ci < 4; ci++) {
        int m = m0 + rt * 16 + lh * 4;
        int c = cb + ci * 16 + lr;
        int bb = m >> 9, n0 = m & 511, hh = c >> 5, dd = c & 31;
        int np = (n0 & ~31) | vperm32(n0 & 31);
        ushort4 w;
        w.x = f2bf(acc[rt][ci][0]);
        w.y = f2bf(acc[rt][ci][1]);
        w.z = f2bf(acc[rt][ci][2]);
        w.w = f2bf(acc[rt][ci][3]);
        *(ushort4*)&Yo[((size_t)(bb * NHEAD + hh) * DH + dd) * NA + np] = w;
      }
  } else {
#pragma unroll
    for (int rt = 0; rt < 2; rt++)
#pragma unroll
      for (int ci = 0; ci < 4; ci++)
#pragma unroll
        for (int r = 0; r < 4; r++) {
          int m = m0 + rt * 16 + lh * 4 + r;
          int c = cb + ci * 16 + lr;
          int bb = m >> 9, n = m & 511, hh = c >> 5, dd = c & 31;
          Yo[((size_t)(bb * NHEAD + hh) * NA + n) * DH + dd] = f2bf(acc[rt][ci][r]);
        }
  }
}

// grid: (32 q-blocks of 16 rows, 16 batch) = 512 blocks (2/CU exact), 512 thr.
// Wave h = head h, all 512 keys (4 tiles of 128, online softmax).
// Bias staged once (1 barrier). V loads: 8 x 16B contiguous per tile (permuted).
__global__ __launch_bounds__(512, 2) void attn_fused(
    const unsigned short* __restrict__ Qw, const unsigned short* __restrict__ Kw,
    const unsigned short* __restrict__ Vtg, const float* __restrict__ X,
    const unsigned char* __restrict__ maskB, const int* __restrict__ maskI,
    const float* __restrict__ adj, float* __restrict__ out) {
  __shared__ float adj_lds[16][ADJ_LD];  // 33,280 B
  const int qb = blockIdx.x, b = blockIdx.y;
  const int t = threadIdx.x;
  const int h = t >> 6, lane = t & 63, lr = lane & 15, lh = lane >> 4;
  const int q0 = qb * 16;
  const size_t bh = (size_t)(b * NHEAD + h) * NA * DH;
  const unsigned short* Kg = Kw + bh;
  const unsigned short* Vg = Vtg + bh;  // [d][n']: d*NA + permuted n

  // Q fragment + K(0) fragments issued first (independent of staging)
  short8 qf = *(const short8*)&Qw[bh + (size_t)(q0 + lr) * DH + lh * 8];
  short8 kf[8];
#pragma unroll
  for (int kt = 0; kt < 8; kt++)
    kf[kt] = *(const short8*)&Kg[(size_t)(kt * 16 + lr) * DH + lh * 8];

  // mask dtype detect (wave-level over first 512 words; wave-uniform result).
  const unsigned int* mu = (const unsigned int*)maskB;
  unsigned int cnt = 0;
#pragma unroll
  for (int j = 0; j < 8; j++) cnt += (mu[lane + j * 64] != 0u) ? 1u : 0u;
#pragma unroll
  for (int off = 32; off > 0; off >>= 1) cnt += __shfl_xor(cnt, off);
  const bool mBytes = (cnt > 368u);

  // stage the full 16x512 bias block (mask merged: masked -> -1e30).
#pragma unroll
  for (int j = 0; j < 4; j++) {
    const int slot = t + j * 512;
    const int srow = slot >> 7;            // 128 float4 per row
    const int sc4 = (slot & 127) * 4;
    const size_t soff = ((size_t)b * NA + q0 + srow) * NA + sc4;
    float4 av = *(const float4*)&adj[soff];
    if (mBytes) {
      uchar4 mb = *(const uchar4*)&maskB[soff];
      if (mb.x) av.x = -1e30f;
      if (mb.y) av.y = -1e30f;
      if (mb.z) av.z = -1e30f;
      if (mb.w) av.w = -1e30f;
    } else {
      int4 mi = *(const int4*)&maskI[soff];
      if (mi.x) av.x = -1e30f;
      if (mi.y) av.y = -1e30f;
      if (mi.z) av.z = -1e30f;
      if (mi.w) av.w = -1e30f;
    }
    *(float4*)&adj_lds[srow][sc4] = av;
  }
  __syncthreads();  // the ONLY barrier

  const floatx4 z = {0.f, 0.f, 0.f, 0.f};
  float m_run = -3.0e38f, l_run = 0.f;  // state for q = q0 + lr (S^T layout)
  floatx4 o0 = z, o1 = z;               // rows q0 + lh*4 + r (C/D layout)

#pragma unroll 1
  for (int tile = 0; tile < 4; ++tile) {
    const int keyoff = tile * 128;

    // (1) V(tile) loads first: 8 x 16B contiguous (permuted layout).
    short8 vf0[4], vf1[4];
#pragma unroll
    for (int kc = 0; kc < 4; kc++) {
      const int kbase = keyoff + kc * 32 + lh * 8;  // contiguous 8 keys
      vf0[kc] = *(const short8*)&Vg[(size_t)lr * NA + kbase];
      vf1[kc] = *(const short8*)&Vg[(size_t)(16 + lr) * NA + kbase];
    }

    // (2) S^T = K * Q^T from the preloaded K buffer
    floatx4 s[8];
#pragma unroll
    for (int kt = 0; kt < 8; kt++) s[kt] = z;
#pragma unroll
    for (int kt = 0; kt < 8; kt++) s[kt] = mfma16(kf[kt], qf, s[kt]);

    // (3) prefetch K(tile+1) — latency hides under softmax + PV
    if (tile < 3) {
      const int nko = keyoff + 128;
#pragma unroll
      for (int kt = 0; kt < 8; kt++)
        kf[kt] = *(const short8*)&Kg[(size_t)(nko + kt * 16 + lr) * DH + lh * 8];
    }

    // (4) bias + softmax (V and K-next in flight underneath)
    float pmax = -3.0e38f;
#pragma unroll
    for (int kt = 0; kt < 8; kt++) {
      float4 av = *(const float4*)&adj_lds[lr][keyoff + kt * 16 + lh * 4];
      float v0 = s[kt][0] * INV_TP + av.x;
      float v1 = s[kt][1] * INV_TP + av.y;
      float v2 = s[kt][2] * INV_TP + av.z;
      float v3 = s[kt][3] * INV_TP + av.w;
      s[kt][0] = v0; s[kt][1] = v1; s[kt][2] = v2; s[kt][3] = v3;
      pmax = fmaxf(pmax, fmaxf(fmaxf(v0, v1), fmaxf(v2, v3)));
    }
    // row q lives in lanes {lr, lr+16, lr+32, lr+48}
    pmax = fmaxf(pmax, __shfl_xor(pmax, 16));
    pmax = fmaxf(pmax, __shfl_xor(pmax, 32));

    const float mnew = fmaxf(m_run, pmax);
    if (tile) {  // tile 0: o/l are zero, skip rescale
      const float corr = __expf(m_run - mnew);
      l_run *= corr;
#pragma unroll
      for (int r = 0; r < 4; r++) {
        float c = __shfl(corr, lh * 4 + r, 64);
        o0[r] *= c;
        o1[r] *= c;
      }
    }
    m_run = mnew;

    float sum = 0.f;
#pragma unroll
    for (int kt = 0; kt < 8; kt++) {
      float e0 = __expf(s[kt][0] - mnew);
      float e1 = __expf(s[kt][1] - mnew);
      float e2 = __expf(s[kt][2] - mnew);
      float e3 = __expf(s[kt][3] - mnew);
      s[kt][0] = e0; s[kt][1] = e1; s[kt][2] = e2; s[kt][3] = e3;
      sum += (e0 + e1) + (e2 + e3);
    }
    sum += __shfl_xor(sum, 16);
    sum += __shfl_xor(sum, 32);
    l_run += sum;

    // (5) PV. A-frag slot j <-> key kc*32 + old(lh*4+j | 16+lh*4+j-4); V stored
    // permuted so B-frag slot j is contiguous position lh*8+j. f2bf packing
    // (validated R17) — NO inline-asm cvt_pk.
#pragma unroll
    for (int kc = 0; kc < 4; kc++) {
      union { short8 s8; unsigned int u[4]; } aa;
      aa.u[0] = (unsigned int)f2bf(s[2 * kc][0]) |
                ((unsigned int)f2bf(s[2 * kc][1]) << 16);
      aa.u[1] = (unsigned int)f2bf(s[2 * kc][2]) |
                ((unsigned int)f2bf(s[2 * kc][3]) << 16);
      aa.u[2] = (unsigned int)f2bf(s[2 * kc + 1][0]) |
                ((unsigned int)f2bf(s[2 * kc + 1][1]) << 16);
      aa.u[3] = (unsigned int)f2bf(s[2 * kc + 1][2]) |
                ((unsigned int)f2bf(s[2 * kc + 1][3]) << 16);
      o0 = mfma16(aa.s8, vf0[kc], o0);
      o1 = mfma16(aa.s8, vf1[kc], o1);
    }
  }

  const float inv = 1.0f / l_run;  // for q = q0 + lr
#pragma unroll
  for (int r = 0; r < 4; r++) {
    float iv = __shfl(inv, lh * 4 + r, 64);  // row q0+lh*4+r's normalizer
    size_t idx = ((size_t)b * NA + (q0 + lh * 4 + r)) * HID + h * DH + lr;
    out[idx] = o0[r] * iv + X[idx];
    out[idx + 16] = o1[r] * iv + X[idx + 16];
  }
}

extern "C" void kernel_launch(void* const* d_in, const int* in_sizes, int n_in,
                              void* d_out, int out_size, void* d_ws, size_t ws_size,
                              hipStream_t stream) {
  const float* x = (const float*)d_in[0];
  const void* mask = d_in[1];
  const float* adj = (const float*)d_in[2];
  const float* Wq = (const float*)d_in[3];
  const float* Wk = (const float*)d_in[4];
  const float* Wv = (const float*)d_in[5];
  float* out = (float*)d_out;

  char* ws = (char*)d_ws;
  const size_t MB = 1048576;
  const size_t NEED = 4 * MB + 512 * 1024 + 3 * 4 * MB;  // Xbf + Wbf + QKV = 16.5MB

  unsigned short *Qw, *Kw, *Vw;
  if (ws_size >= NEED) {
    unsigned short* Xbf = (unsigned short*)ws;                   // 4 MB
    unsigned short* Wbf = (unsigned short*)(ws + 4 * MB);        // 384 KB (+pad)
    Qw = (unsigned short*)(ws + 4 * MB + 512 * 1024);            // 4 MB
    Kw = (unsigned short*)(ws + 8 * MB + 512 * 1024);            // 4 MB
    Vw = (unsigned short*)(ws + 12 * MB + 512 * 1024);           // 4 MB (transposed+permuted)
    cvt_bf16<<<1024, 256, 0, stream>>>(x, Wq, Wk, Wv, Xbf, Wbf);
    qkv_proj_bf<<<dim3(256, 3), 256, 0, stream>>>(Xbf, Wbf, Qw);
  } else {
    Qw = (unsigned short*)(ws + 4096);
    Kw = (unsigned short*)(ws + 4096 + 4 * MB);
    Vw = (unsigned short*)(ws + 4096 + 8 * MB);
    qkv_proj<<<dim3(256, 3), 256, 0, stream>>>(x, Wq, Wk, Wv, Qw);
  }
  attn_fused<<<dim3(32, NB), 512, 0, stream>>>(
      Qw, Kw, Vw, x, (const unsigned char*)mask, (const int*)mask, adj, out);
}

// Round 22
// 60.955 us; speedup vs baseline: 1.2245x; 1.0086x over previous
//
#include <hip/hip_runtime.h>
#include <hip/hip_bf16.h>

// MultiHeadAttention: x(16,512,256) f32; mask(1,16,512,512) bool; adj(1,16,512,512) f32;
// Wq/Wk/Wv (256,256) f32.  out = softmax(QK^T/sqrt(64) + adj, mask) @ V + x, f32.
// R21: pin the load schedule with sched_barrier(0). R20's VGPR=72 proves the
// compiler sank the V/K load batches to their uses (hand schedule needs ~123
// live regs) -> ~90 serialized full-latency loads/wave = the 96k-cycle wall.
// Fences: after V-load issue; after QK+K-prefetch. Gate: VGPR must rise >=100.
// Everything else = R20 (V-permute validated, f2bf packing, 1 barrier).

#define NB 16
#define NA 512
#define HID 256
#define NHEAD 8
#define DH 32
#define INV_TP 0.125f  // 1/sqrt(2*32)
#define ADJ_LD 520     // 512 cols + 8 pad (f32)

typedef __attribute__((ext_vector_type(8))) short short8;   // 8 bf16 MFMA frag
typedef __attribute__((ext_vector_type(4))) float floatx4;  // MFMA acc

__device__ __forceinline__ unsigned short f2bf(float f) {
  unsigned int u = __builtin_bit_cast(unsigned int, f);
  u += 0x7fffu + ((u >> 16) & 1u);  // round-to-nearest-even
  return (unsigned short)(u >> 16);
}

__device__ __forceinline__ floatx4 mfma16(short8 a, short8 b, floatx4 c) {
  return __builtin_amdgcn_mfma_f32_16x16x32_bf16(a, b, c, 0, 0, 0);
}

__device__ __forceinline__ short8 ld8f32_bf16(const float* __restrict__ p) {
  float4 a = *(const float4*)p;
  float4 b = *(const float4*)(p + 4);
  short8 r;
  r[0] = (short)f2bf(a.x); r[1] = (short)f2bf(a.y);
  r[2] = (short)f2bf(a.z); r[3] = (short)f2bf(a.w);
  r[4] = (short)f2bf(b.x); r[5] = (short)f2bf(b.y);
  r[6] = (short)f2bf(b.z); r[7] = (short)f2bf(b.w);
  return r;
}

// V key permutation within each 32-key group: old g -> new position.
// Makes PV B-frag keys contiguous per (kc, lh): new = lh*8 + (0..7).
__device__ __forceinline__ int vperm32(int g) {
  return (((g & 15) >> 2) << 3) + (g & 3) + (((g >> 4) & 1) << 2);
}

// Streaming f32->bf16 for X (2M elems) and Wq/Wk/Wv (64K each). Memory-bound.
__global__ __launch_bounds__(256) void cvt_bf16(
    const float* __restrict__ X, const float* __restrict__ Wq,
    const float* __restrict__ Wk, const float* __restrict__ Wv,
    unsigned short* __restrict__ Xbf, unsigned short* __restrict__ Wbf) {
  const int tid = blockIdx.x * blockDim.x + threadIdx.x;
  const int stride = gridDim.x * blockDim.x;
  for (int i = tid; i < (NB * NA * HID) / 4; i += stride) {
    float4 v = ((const float4*)X)[i];
    ushort4 w;
    w.x = f2bf(v.x); w.y = f2bf(v.y); w.z = f2bf(v.z); w.w = f2bf(v.w);
    ((ushort4*)Xbf)[i] = w;
  }
  for (int i = tid; i < (HID * HID) / 4; i += stride) {
    float4 v = ((const float4*)Wq)[i];
    ushort4 w;
    w.x = f2bf(v.x); w.y = f2bf(v.y); w.z = f2bf(v.z); w.w = f2bf(v.w);
    ((ushort4*)Wbf)[i] = w;
    v = ((const float4*)Wk)[i];
    w.x = f2bf(v.x); w.y = f2bf(v.y); w.z = f2bf(v.z); w.w = f2bf(v.w);
    ((ushort4*)(Wbf + HID * HID))[i] = w;
    v = ((const float4*)Wv)[i];
    w.x = f2bf(v.x); w.y = f2bf(v.y); w.z = f2bf(v.z); w.w = f2bf(v.w);
    ((ushort4*)(Wbf + 2 * HID * HID))[i] = w;
  }
}

// Pure-bf16 projection: Y[m][c] = sum_k Xbf[m][k] * Wbf[c][k].
// Q,K stored [b][h][n][d]; V stored TRANSPOSED [b][h][d][n'] with n' = key-
// permuted within 32-groups (vperm32) so attn PV loads are 16B-contiguous.
__global__ __launch_bounds__(256) void qkv_proj_bf(
    const unsigned short* __restrict__ Xbf, const unsigned short* __restrict__ Wbf,
    unsigned short* __restrict__ Y) {
  const unsigned short* W = Wbf + (size_t)blockIdx.y * (HID * HID);
  unsigned short* Yo = Y + (size_t)blockIdx.y * (NB * NHEAD * NA * DH);
  const int wave = threadIdx.x >> 6, lane = threadIdx.x & 63;
  const int lr = lane & 15, lh = lane >> 4;
  const int m0 = blockIdx.x * 32;
  const int cb = wave * 64;
  const floatx4 z = {0.f, 0.f, 0.f, 0.f};
  floatx4 acc[2][4];
#pragma unroll
  for (int i = 0; i < 2; i++)
#pragma unroll
    for (int j = 0; j < 4; j++) acc[i][j] = z;

  for (int kb = 0; kb < HID; kb += 32) {
    short8 a[2], bw[4];
#pragma unroll
    for (int rt = 0; rt < 2; rt++)
      a[rt] = *(const short8*)&Xbf[(size_t)(m0 + rt * 16 + lr) * HID + kb + lh * 8];
#pragma unroll
    for (int ci = 0; ci < 4; ci++)
      bw[ci] = *(const short8*)&W[(size_t)(cb + ci * 16 + lr) * HID + kb + lh * 8];
#pragma unroll
    for (int rt = 0; rt < 2; rt++)
#pragma unroll
      for (int ci = 0; ci < 4; ci++)
        acc[rt][ci] = mfma16(a[rt], bw[ci], acc[rt][ci]);
  }
  if (blockIdx.y == 2) {
    // V: [b][h][d][n'], 4 consecutive keys -> contiguous permuted positions.
#pragma unroll
    for (int rt = 0; rt < 2; rt++)
#pragma unroll
      for (int ci = 0; ci < 4; ci++) {
        int m = m0 + rt * 16 + lh * 4;       // keys m..m+3 (same batch: 32|512)
        int c = cb + ci * 16 + lr;
        int bb = m >> 9, n0 = m & 511, hh = c >> 5, dd = c & 31;
        int np = (n0 & ~31) | vperm32(n0 & 31);  // 4-aligned, stays contiguous
        ushort4 w;
        w.x = f2bf(acc[rt][ci][0]);
        w.y = f2bf(acc[rt][ci][1]);
        w.z = f2bf(acc[rt][ci][2]);
        w.w = f2bf(acc[rt][ci][3]);
        *(ushort4*)&Yo[((size_t)(bb * NHEAD + hh) * DH + dd) * NA + np] = w;
      }
  } else {
#pragma unroll
    for (int rt = 0; rt < 2; rt++)
#pragma unroll
      for (int ci = 0; ci < 4; ci++)
#pragma unroll
        for (int r = 0; r < 4; r++) {
          int m = m0 + rt * 16 + lh * 4 + r;   // D layout: row=(l>>4)*4+reg
          int c = cb + ci * 16 + lr;           //           col=l&15
          int bb = m >> 9, n = m & 511, hh = c >> 5, dd = c & 31;
          Yo[((size_t)(bb * NHEAD + hh) * NA + n) * DH + dd] = f2bf(acc[rt][ci][r]);
        }
  }
}

// Fallback projection: inline f32->bf16. Used only if ws too small.
__global__ __launch_bounds__(256) void qkv_proj(
    const float* __restrict__ X, const float* __restrict__ Wq,
    const float* __restrict__ Wk, const float* __restrict__ Wv,
    unsigned short* __restrict__ Y) {
  const float* W = (blockIdx.y == 0) ? Wq : (blockIdx.y == 1) ? Wk : Wv;
  unsigned short* Yo = Y + (size_t)blockIdx.y * (NB * NHEAD * NA * DH);
  const int wave = threadIdx.x >> 6, lane = threadIdx.x & 63;
  const int lr = lane & 15, lh = lane >> 4;
  const int m0 = blockIdx.x * 32;
  const int cb = wave * 64;
  const floatx4 z = {0.f, 0.f, 0.f, 0.f};
  floatx4 acc[2][4];
#pragma unroll
  for (int i = 0; i < 2; i++)
#pragma unroll
    for (int j = 0; j < 4; j++) acc[i][j] = z;

  for (int kb = 0; kb < HID; kb += 32) {
    short8 a[2], bw[4];
#pragma unroll
    for (int rt = 0; rt < 2; rt++)
      a[rt] = ld8f32_bf16(X + (size_t)(m0 + rt * 16 + lr) * HID + kb + lh * 8);
#pragma unroll
    for (int ci = 0; ci < 4; ci++)
      bw[ci] = ld8f32_bf16(W + (size_t)(cb + ci * 16 + lr) * HID + kb + lh * 8);
#pragma unroll
    for (int rt = 0; rt < 2; rt++)
#pragma unroll
      for (int ci = 0; ci < 4; ci++)
        acc[rt][ci] = mfma16(a[rt], bw[ci], acc[rt][ci]);
  }
  if (blockIdx.y == 2) {
#pragma unroll
    for (int rt = 0; rt < 2; rt++)
#pragma unroll
      for (int ci = 0; ci < 4; ci++) {
        int m = m0 + rt * 16 + lh * 4;
        int c = cb + ci * 16 + lr;
        int bb = m >> 9, n0 = m & 511, hh = c >> 5, dd = c & 31;
        int np = (n0 & ~31) | vperm32(n0 & 31);
        ushort4 w;
        w.x = f2bf(acc[rt][ci][0]);
        w.y = f2bf(acc[rt][ci][1]);
        w.z = f2bf(acc[rt][ci][2]);
        w.w = f2bf(acc[rt][ci][3]);
        *(ushort4*)&Yo[((size_t)(bb * NHEAD + hh) * DH + dd) * NA + np] = w;
      }
  } else {
#pragma unroll
    for (int rt = 0; rt < 2; rt++)
#pragma unroll
      for (int ci = 0; ci < 4; ci++)
#pragma unroll
        for (int r = 0; r < 4; r++) {
          int m = m0 + rt * 16 + lh * 4 + r;
          int c = cb + ci * 16 + lr;
          int bb = m >> 9, n = m & 511, hh = c >> 5, dd = c & 31;
          Yo[((size_t)(bb * NHEAD + hh) * NA + n) * DH + dd] = f2bf(acc[rt][ci][r]);
        }
  }
}

// grid: (32 q-blocks of 16 rows, 16 batch) = 512 blocks, 512 thr.
// Wave h = head h, all 512 keys (4 tiles of 128, online softmax).
// Bias staged once (1 barrier). Load schedule PINNED with sched_barrier(0).
__global__ __launch_bounds__(512, 2) void attn_fused(
    const unsigned short* __restrict__ Qw, const unsigned short* __restrict__ Kw,
    const unsigned short* __restrict__ Vtg, const float* __restrict__ X,
    const unsigned char* __restrict__ maskB, const int* __restrict__ maskI,
    const float* __restrict__ adj, float* __restrict__ out) {
  __shared__ float adj_lds[16][ADJ_LD];  // 33,280 B
  const int qb = blockIdx.x, b = blockIdx.y;
  const int t = threadIdx.x;
  const int h = t >> 6, lane = t & 63, lr = lane & 15, lh = lane >> 4;
  const int q0 = qb * 16;
  const size_t bh = (size_t)(b * NHEAD + h) * NA * DH;
  const unsigned short* Kg = Kw + bh;
  const unsigned short* Vg = Vtg + bh;  // [d][n']: d*NA + permuted n

  // Q fragment + K(0) fragments issued first (independent of staging)
  short8 qf = *(const short8*)&Qw[bh + (size_t)(q0 + lr) * DH + lh * 8];
  short8 kf[8];
#pragma unroll
  for (int kt = 0; kt < 8; kt++)
    kf[kt] = *(const short8*)&Kg[(size_t)(kt * 16 + lr) * DH + lh * 8];

  // mask dtype detect (wave-level over first 512 words; wave-uniform result).
  const unsigned int* mu = (const unsigned int*)maskB;
  unsigned int cnt = 0;
#pragma unroll
  for (int j = 0; j < 8; j++) cnt += (mu[lane + j * 64] != 0u) ? 1u : 0u;
#pragma unroll
  for (int off = 32; off > 0; off >>= 1) cnt += __shfl_xor(cnt, off);
  const bool mBytes = (cnt > 368u);

  // stage the full 16x512 bias block (mask merged: masked -> -1e30).
#pragma unroll
  for (int j = 0; j < 4; j++) {
    const int slot = t + j * 512;
    const int srow = slot >> 7;            // 128 float4 per row
    const int sc4 = (slot & 127) * 4;
    const size_t soff = ((size_t)b * NA + q0 + srow) * NA + sc4;
    float4 av = *(const float4*)&adj[soff];
    if (mBytes) {
      uchar4 mb = *(const uchar4*)&maskB[soff];
      if (mb.x) av.x = -1e30f;
      if (mb.y) av.y = -1e30f;
      if (mb.z) av.z = -1e30f;
      if (mb.w) av.w = -1e30f;
    } else {
      int4 mi = *(const int4*)&maskI[soff];
      if (mi.x) av.x = -1e30f;
      if (mi.y) av.y = -1e30f;
      if (mi.z) av.z = -1e30f;
      if (mi.w) av.w = -1e30f;
    }
    *(float4*)&adj_lds[srow][sc4] = av;
  }
  __syncthreads();  // the ONLY barrier

  const floatx4 z = {0.f, 0.f, 0.f, 0.f};
  float m_run = -3.0e38f, l_run = 0.f;  // state for q = q0 + lr (S^T layout)
  floatx4 o0 = z, o1 = z;               // rows q0 + lh*4 + r (C/D layout)

#pragma unroll 1
  for (int tile = 0; tile < 4; ++tile) {
    const int keyoff = tile * 128;

    // (1) V(tile) loads first: 8 x 16B contiguous (permuted layout).
    short8 vf0[4], vf1[4];
#pragma unroll
    for (int kc = 0; kc < 4; kc++) {
      const int kbase = keyoff + kc * 32 + lh * 8;  // contiguous 8 keys
      vf0[kc] = *(const short8*)&Vg[(size_t)lr * NA + kbase];
      vf1[kc] = *(const short8*)&Vg[(size_t)(16 + lr) * NA + kbase];
    }
    // pin: V loads may not sink below this point
    __builtin_amdgcn_sched_barrier(0);

    // (2) S^T = K * Q^T from the preloaded K buffer
    floatx4 s[8];
#pragma unroll
    for (int kt = 0; kt < 8; kt++) s[kt] = z;
#pragma unroll
    for (int kt = 0; kt < 8; kt++) s[kt] = mfma16(kf[kt], qf, s[kt]);

    // (3) prefetch K(tile+1) — latency hides under softmax + PV
    if (tile < 3) {
      const int nko = keyoff + 128;
#pragma unroll
      for (int kt = 0; kt < 8; kt++)
        kf[kt] = *(const short8*)&Kg[(size_t)(nko + kt * 16 + lr) * DH + lh * 8];
    }
    // pin: QK + K-prefetch stay above; softmax stays below
    __builtin_amdgcn_sched_barrier(0);

    // (4) bias + softmax (V and K-next in flight underneath)
    float pmax = -3.0e38f;
#pragma unroll
    for (int kt = 0; kt < 8; kt++) {
      float4 av = *(const float4*)&adj_lds[lr][keyoff + kt * 16 + lh * 4];
      float v0 = s[kt][0] * INV_TP + av.x;
      float v1 = s[kt][1] * INV_TP + av.y;
      float v2 = s[kt][2] * INV_TP + av.z;
      float v3 = s[kt][3] * INV_TP + av.w;
      s[kt][0] = v0; s[kt][1] = v1; s[kt][2] = v2; s[kt][3] = v3;
      pmax = fmaxf(pmax, fmaxf(fmaxf(v0, v1), fmaxf(v2, v3)));
    }
    // row q lives in lanes {lr, lr+16, lr+32, lr+48}
    pmax = fmaxf(pmax, __shfl_xor(pmax, 16));
    pmax = fmaxf(pmax, __shfl_xor(pmax, 32));

    const float mnew = fmaxf(m_run, pmax);
    if (tile) {  // tile 0: o/l are zero, skip rescale
      const float corr = __expf(m_run - mnew);
      l_run *= corr;
#pragma unroll
      for (int r = 0; r < 4; r++) {
        float c = __shfl(corr, lh * 4 + r, 64);
        o0[r] *= c;
        o1[r] *= c;
      }
    }
    m_run = mnew;

    float sum = 0.f;
#pragma unroll
    for (int kt = 0; kt < 8; kt++) {
      float e0 = __expf(s[kt][0] - mnew);
      float e1 = __expf(s[kt][1] - mnew);
      float e2 = __expf(s[kt][2] - mnew);
      float e3 = __expf(s[kt][3] - mnew);
      s[kt][0] = e0; s[kt][1] = e1; s[kt][2] = e2; s[kt][3] = e3;
      sum += (e0 + e1) + (e2 + e3);
    }
    sum += __shfl_xor(sum, 16);
    sum += __shfl_xor(sum, 32);
    l_run += sum;

    // (5) PV. A-frag slot j <-> key kc*32 + old(lh*4+j | 16+lh*4+j-4); V stored
    // permuted so B-frag slot j is contiguous position lh*8+j. f2bf packing.
#pragma unroll
    for (int kc = 0; kc < 4; kc++) {
      union { short8 s8; unsigned int u[4]; } aa;
      aa.u[0] = (unsigned int)f2bf(s[2 * kc][0]) |
                ((unsigned int)f2bf(s[2 * kc][1]) << 16);
      aa.u[1] = (unsigned int)f2bf(s[2 * kc][2]) |
                ((unsigned int)f2bf(s[2 * kc][3]) << 16);
      aa.u[2] = (unsigned int)f2bf(s[2 * kc + 1][0]) |
                ((unsigned int)f2bf(s[2 * kc + 1][1]) << 16);
      aa.u[3] = (unsigned int)f2bf(s[2 * kc + 1][2]) |
                ((unsigned int)f2bf(s[2 * kc + 1][3]) << 16);
      o0 = mfma16(aa.s8, vf0[kc], o0);
      o1 = mfma16(aa.s8, vf1[kc], o1);
    }
  }

  const float inv = 1.0f / l_run;  // for q = q0 + lr
#pragma unroll
  for (int r = 0; r < 4; r++) {
    float iv = __shfl(inv, lh * 4 + r, 64);  // row q0+lh*4+r's normalizer
    size_t idx = ((size_t)b * NA + (q0 + lh * 4 + r)) * HID + h * DH + lr;
    out[idx] = o0[r] * iv + X[idx];
    out[idx + 16] = o1[r] * iv + X[idx + 16];
  }
}

extern "C" void kernel_launch(void* const* d_in, const int* in_sizes, int n_in,
                              void* d_out, int out_size, void* d_ws, size_t ws_size,
                              hipStream_t stream) {
  const float* x = (const float*)d_in[0];
  const void* mask = d_in[1];
  const float* adj = (const float*)d_in[2];
  const float* Wq = (const float*)d_in[3];
  const float* Wk = (const float*)d_in[4];
  const float* Wv = (const float*)d_in[5];
  float* out = (float*)d_out;

  char* ws = (char*)d_ws;
  const size_t MB = 1048576;
  const size_t NEED = 4 * MB + 512 * 1024 + 3 * 4 * MB;  // Xbf + Wbf + QKV = 16.5MB

  unsigned short *Qw, *Kw, *Vw;
  if (ws_size >= NEED) {
    unsigned short* Xbf = (unsigned short*)ws;                   // 4 MB
    unsigned short* Wbf = (unsigned short*)(ws + 4 * MB);        // 384 KB (+pad)
    Qw = (unsigned short*)(ws + 4 * MB + 512 * 1024);            // 4 MB
    Kw = (unsigned short*)(ws + 8 * MB + 512 * 1024);            // 4 MB
    Vw = (unsigned short*)(ws + 12 * MB + 512 * 1024);           // 4 MB (transposed+permuted)
    cvt_bf16<<<1024, 256, 0, stream>>>(x, Wq, Wk, Wv, Xbf, Wbf);
    qkv_proj_bf<<<dim3(256, 3), 256, 0, stream>>>(Xbf, Wbf, Qw);
  } else {
    Qw = (unsigned short*)(ws + 4096);
    Kw = (unsigned short*)(ws + 4096 + 4 * MB);
    Vw = (unsigned short*)(ws + 4096 + 8 * MB);
    qkv_proj<<<dim3(256, 3), 256, 0, stream>>>(x, Wq, Wk, Wv, Qw);
  }
  attn_fused<<<dim3(32, NB), 512, 0, stream>>>(
      Qw, Kw, Vw, x, (const unsigned char*)mask, (const int*)mask, adj, out);
}

// Round 24
// 58.383 us; speedup vs baseline: 1.2785x; 1.0440x over previous
//
#include <hip/hip_runtime.h>
#include <hip/hip_bf16.h>

// MultiHeadAttention: x(16,512,256) f32; mask(1,16,512,512) bool; adj(1,16,512,512) f32;
// Wq/Wk/Wv (256,256) f32.  out = softmax(QK^T/sqrt(64) + adj, mask) @ V + x, f32.
// R22: tail restructure (attn untouched = R21, ~36us, validated).
//  - cvt_w: W-only bf16 convert (0.77MB, ~1us). Xbf global round-trip DELETED.
//  - qkv_fused: block converts its 32 X-rows once into LDS (A-frags from LDS),
//    GEMM vs Wbf; Q/K epilogue staged in LDS -> 4x16B coalesced stores/thread
//    (was 16x2B scalar — the R20-proven transaction disease). V stores direct.
// Predicted: tail 25 -> ~16-18us, total 61 -> ~52-56. Gate: >=59 => launch gaps.

#define NB 16
#define NA 512
#define HID 256
#define NHEAD 8
#define DH 32
#define INV_TP 0.125f  // 1/sqrt(2*32)
#define ADJ_LD 520     // 512 cols + 8 pad (f32)
#define XT_LD 264      // 256 cols + 8 pad (bf16), row stride 528B (16B-aligned)

typedef __attribute__((ext_vector_type(8))) short short8;   // 8 bf16 MFMA frag
typedef __attribute__((ext_vector_type(4))) float floatx4;  // MFMA acc

__device__ __forceinline__ unsigned short f2bf(float f) {
  unsigned int u = __builtin_bit_cast(unsigned int, f);
  u += 0x7fffu + ((u >> 16) & 1u);  // round-to-nearest-even
  return (unsigned short)(u >> 16);
}

__device__ __forceinline__ floatx4 mfma16(short8 a, short8 b, floatx4 c) {
  return __builtin_amdgcn_mfma_f32_16x16x32_bf16(a, b, c, 0, 0, 0);
}

__device__ __forceinline__ short8 ld8f32_bf16(const float* __restrict__ p) {
  float4 a = *(const float4*)p;
  float4 b = *(const float4*)(p + 4);
  short8 r;
  r[0] = (short)f2bf(a.x); r[1] = (short)f2bf(a.y);
  r[2] = (short)f2bf(a.z); r[3] = (short)f2bf(a.w);
  r[4] = (short)f2bf(b.x); r[5] = (short)f2bf(b.y);
  r[6] = (short)f2bf(b.z); r[7] = (short)f2bf(b.w);
  return r;
}

// V key permutation within each 32-key group: old g -> new position.
// Makes PV B-frag keys contiguous per (kc, lh): new = lh*8 + (0..7).
__device__ __forceinline__ int vperm32(int g) {
  return (((g & 15) >> 2) << 3) + (g & 3) + (((g >> 4) & 1) << 2);
}

// W-only f32->bf16 (3 x 64K elems). ~1us.
__global__ __launch_bounds__(256) void cvt_w(
    const float* __restrict__ Wq, const float* __restrict__ Wk,
    const float* __restrict__ Wv, unsigned short* __restrict__ Wbf) {
  const int tid = blockIdx.x * blockDim.x + threadIdx.x;
  const int stride = gridDim.x * blockDim.x;
  for (int i = tid; i < (HID * HID) / 4; i += stride) {
    float4 v = ((const float4*)Wq)[i];
    ushort4 w;
    w.x = f2bf(v.x); w.y = f2bf(v.y); w.z = f2bf(v.z); w.w = f2bf(v.w);
    ((ushort4*)Wbf)[i] = w;
    v = ((const float4*)Wk)[i];
    w.x = f2bf(v.x); w.y = f2bf(v.y); w.z = f2bf(v.z); w.w = f2bf(v.w);
    ((ushort4*)(Wbf + HID * HID))[i] = w;
    v = ((const float4*)Wv)[i];
    w.x = f2bf(v.x); w.y = f2bf(v.y); w.z = f2bf(v.z); w.w = f2bf(v.w);
    ((ushort4*)(Wbf + 2 * HID * HID))[i] = w;
  }
}

// Fused projection: convert 32 X-rows to LDS once, GEMM vs Wbf, coalesced
// epilogue. grid (256, 3); block 256 (4 waves x 64 cols).
// Q,K stored [b][h][n][d]; V stored TRANSPOSED+permuted [b][h][d][n'].
__global__ __launch_bounds__(256) void qkv_fused(
    const float* __restrict__ X, const unsigned short* __restrict__ Wbf,
    unsigned short* __restrict__ Y) {
  __shared__ __align__(16) unsigned short xt[32][XT_LD];  // 16,896 B (reused)
  const unsigned short* W = Wbf + (size_t)blockIdx.y * (HID * HID);
  unsigned short* Yo = Y + (size_t)blockIdx.y * (NB * NHEAD * NA * DH);
  const int t = threadIdx.x;
  const int wave = t >> 6, lane = t & 63;
  const int lr = lane & 15, lh = lane >> 4;
  const int m0 = blockIdx.x * 32;
  const int cb = wave * 64;

  // Phase 1: convert own X tile (32 rows x 256) into LDS.
  {
    const int r = t >> 3, c0 = (t & 7) * 32;
    const float* xrow = X + (size_t)(m0 + r) * HID + c0;
#pragma unroll
    for (int j = 0; j < 8; j++) {
      float4 v = ((const float4*)xrow)[j];
      ushort4 w;
      w.x = f2bf(v.x); w.y = f2bf(v.y); w.z = f2bf(v.z); w.w = f2bf(v.w);
      *(ushort4*)&xt[r][c0 + j * 4] = w;
    }
  }
  __syncthreads();

  // Phase 2: GEMM. A from LDS, B from Wbf (L2-resident).
  const floatx4 z = {0.f, 0.f, 0.f, 0.f};
  floatx4 acc[2][4];
#pragma unroll
  for (int i = 0; i < 2; i++)
#pragma unroll
    for (int j = 0; j < 4; j++) acc[i][j] = z;

  for (int kb = 0; kb < HID; kb += 32) {
    short8 a[2], bw[4];
#pragma unroll
    for (int rt = 0; rt < 2; rt++)
      a[rt] = *(const short8*)&xt[rt * 16 + lr][kb + lh * 8];
#pragma unroll
    for (int ci = 0; ci < 4; ci++)
      bw[ci] = *(const short8*)&W[(size_t)(cb + ci * 16 + lr) * HID + kb + lh * 8];
#pragma unroll
    for (int rt = 0; rt < 2; rt++)
#pragma unroll
      for (int ci = 0; ci < 4; ci++)
        acc[rt][ci] = mfma16(a[rt], bw[ci], acc[rt][ci]);
  }
  __syncthreads();  // all LDS A-reads done; xt reusable

  if (blockIdx.y == 2) {
    // V: direct permuted stores (validated): [b][h][d][n'], ushort4 each.
#pragma unroll
    for (int rt = 0; rt < 2; rt++)
#pragma unroll
      for (int ci = 0; ci < 4; ci++) {
        int m = m0 + rt * 16 + lh * 4;       // keys m..m+3 (same batch: 32|512)
        int c = cb + ci * 16 + lr;
        int bb = m >> 9, n0 = m & 511, hh = c >> 5, dd = c & 31;
        int np = (n0 & ~31) | vperm32(n0 & 31);  // 4-aligned, stays contiguous
        ushort4 w;
        w.x = f2bf(acc[rt][ci][0]);
        w.y = f2bf(acc[rt][ci][1]);
        w.z = f2bf(acc[rt][ci][2]);
        w.w = f2bf(acc[rt][ci][3]);
        *(ushort4*)&Yo[((size_t)(bb * NHEAD + hh) * DH + dd) * NA + np] = w;
      }
    __syncthreads();  // match Q/K path barrier
  } else {
    // Q/K: stage tile in LDS (D-layout scatter, cheap 2B LDS writes), then
    // 4 x 16B coalesced global stores per thread.
#pragma unroll
    for (int rt = 0; rt < 2; rt++)
#pragma unroll
      for (int ci = 0; ci < 4; ci++)
#pragma unroll
        for (int r = 0; r < 4; r++)
          xt[rt * 16 + lh * 4 + r][cb + ci * 16 + lr] = f2bf(acc[rt][ci][r]);
    __syncthreads();
#pragma unroll
    for (int j = 0; j < 4; j++) {
      const int chunk = t + j * 256;        // 1024 chunks of 8 cols
      const int row = chunk >> 5;           // 0..31
      const int c0 = (chunk & 31) * 8;      // 0..248, within one head
      const int n = m0 + row;
      const int bb = n >> 9, nn = n & 511, hh = c0 >> 5, dd = c0 & 31;
      *(uint4*)&Yo[((size_t)(bb * NHEAD + hh) * NA + nn) * DH + dd] =
          *(const uint4*)&xt[row][c0];
    }
  }
}

// Fallback projection (f32 direct, inline cvt). Used only if ws too small.
__global__ __launch_bounds__(256) void qkv_proj(
    const float* __restrict__ X, const float* __restrict__ Wq,
    const float* __restrict__ Wk, const float* __restrict__ Wv,
    unsigned short* __restrict__ Y) {
  const float* W = (blockIdx.y == 0) ? Wq : (blockIdx.y == 1) ? Wk : Wv;
  unsigned short* Yo = Y + (size_t)blockIdx.y * (NB * NHEAD * NA * DH);
  const int wave = threadIdx.x >> 6, lane = threadIdx.x & 63;
  const int lr = lane & 15, lh = lane >> 4;
  const int m0 = blockIdx.x * 32;
  const int cb = wave * 64;
  const floatx4 z = {0.f, 0.f, 0.f, 0.f};
  floatx4 acc[2][4];
#pragma unroll
  for (int i = 0; i < 2; i++)
#pragma unroll
    for (int j = 0; j < 4; j++) acc[i][j] = z;

  for (int kb = 0; kb < HID; kb += 32) {
    short8 a[2], bw[4];
#pragma unroll
    for (int rt = 0; rt < 2; rt++)
      a[rt] = ld8f32_bf16(X + (size_t)(m0 + rt * 16 + lr) * HID + kb + lh * 8);
#pragma unroll
    for (int ci = 0; ci < 4; ci++)
      bw[ci] = ld8f32_bf16(W + (size_t)(cb + ci * 16 + lr) * HID + kb + lh * 8);
#pragma unroll
    for (int rt = 0; rt < 2; rt++)
#pragma unroll
      for (int ci = 0; ci < 4; ci++)
        acc[rt][ci] = mfma16(a[rt], bw[ci], acc[rt][ci]);
  }
  if (blockIdx.y == 2) {
#pragma unroll
    for (int rt = 0; rt < 2; rt++)
#pragma unroll
      for (int ci = 0; ci < 4; ci++) {
        int m = m0 + rt * 16 + lh * 4;
        int c = cb + ci * 16 + lr;
        int bb = m >> 9, n0 = m & 511, hh = c >> 5, dd = c & 31;
        int np = (n0 & ~31) | vperm32(n0 & 31);
        ushort4 w;
        w.x = f2bf(acc[rt][ci][0]);
        w.y = f2bf(acc[rt][ci][1]);
        w.z = f2bf(acc[rt][ci][2]);
        w.w = f2bf(acc[rt][ci][3]);
        *(ushort4*)&Yo[((size_t)(bb * NHEAD + hh) * DH + dd) * NA + np] = w;
      }
  } else {
#pragma unroll
    for (int rt = 0; rt < 2; rt++)
#pragma unroll
      for (int ci = 0; ci < 4; ci++)
#pragma unroll
        for (int r = 0; r < 4; r++) {
          int m = m0 + rt * 16 + lh * 4 + r;
          int c = cb + ci * 16 + lr;
          int bb = m >> 9, n = m & 511, hh = c >> 5, dd = c & 31;
          Yo[((size_t)(bb * NHEAD + hh) * NA + n) * DH + dd] = f2bf(acc[rt][ci][r]);
        }
  }
}

// grid: (32 q-blocks of 16 rows, 16 batch) = 512 blocks, 512 thr.
// Wave h = head h, all 512 keys (4 tiles of 128, online softmax).
// Bias staged once (1 barrier). Load schedule pinned with sched_barrier(0).
__global__ __launch_bounds__(512, 2) void attn_fused(
    const unsigned short* __restrict__ Qw, const unsigned short* __restrict__ Kw,
    const unsigned short* __restrict__ Vtg, const float* __restrict__ X,
    const unsigned char* __restrict__ maskB, const int* __restrict__ maskI,
    const float* __restrict__ adj, float* __restrict__ out) {
  __shared__ float adj_lds[16][ADJ_LD];  // 33,280 B
  const int qb = blockIdx.x, b = blockIdx.y;
  const int t = threadIdx.x;
  const int h = t >> 6, lane = t & 63, lr = lane & 15, lh = lane >> 4;
  const int q0 = qb * 16;
  const size_t bh = (size_t)(b * NHEAD + h) * NA * DH;
  const unsigned short* Kg = Kw + bh;
  const unsigned short* Vg = Vtg + bh;  // [d][n']: d*NA + permuted n

  // Q fragment + K(0) fragments issued first (independent of staging)
  short8 qf = *(const short8*)&Qw[bh + (size_t)(q0 + lr) * DH + lh * 8];
  short8 kf[8];
#pragma unroll
  for (int kt = 0; kt < 8; kt++)
    kf[kt] = *(const short8*)&Kg[(size_t)(kt * 16 + lr) * DH + lh * 8];

  // mask dtype detect (wave-level over first 512 words; wave-uniform result).
  const unsigned int* mu = (const unsigned int*)maskB;
  unsigned int cnt = 0;
#pragma unroll
  for (int j = 0; j < 8; j++) cnt += (mu[lane + j * 64] != 0u) ? 1u : 0u;
#pragma unroll
  for (int off = 32; off > 0; off >>= 1) cnt += __shfl_xor(cnt, off);
  const bool mBytes = (cnt > 368u);

  // stage the full 16x512 bias block (mask merged: masked -> -1e30).
#pragma unroll
  for (int j = 0; j < 4; j++) {
    const int slot = t + j * 512;
    const int srow = slot >> 7;            // 128 float4 per row
    const int sc4 = (slot & 127) * 4;
    const size_t soff = ((size_t)b * NA + q0 + srow) * NA + sc4;
    float4 av = *(const float4*)&adj[soff];
    if (mBytes) {
      uchar4 mb = *(const uchar4*)&maskB[soff];
      if (mb.x) av.x = -1e30f;
      if (mb.y) av.y = -1e30f;
      if (mb.z) av.z = -1e30f;
      if (mb.w) av.w = -1e30f;
    } else {
      int4 mi = *(const int4*)&maskI[soff];
      if (mi.x) av.x = -1e30f;
      if (mi.y) av.y = -1e30f;
      if (mi.z) av.z = -1e30f;
      if (mi.w) av.w = -1e30f;
    }
    *(float4*)&adj_lds[srow][sc4] = av;
  }
  __syncthreads();  // the ONLY barrier

  const floatx4 z = {0.f, 0.f, 0.f, 0.f};
  float m_run = -3.0e38f, l_run = 0.f;  // state for q = q0 + lr (S^T layout)
  floatx4 o0 = z, o1 = z;               // rows q0 + lh*4 + r (C/D layout)

#pragma unroll 1
  for (int tile = 0; tile < 4; ++tile) {
    const int keyoff = tile * 128;

    // (1) V(tile) loads first: 8 x 16B contiguous (permuted layout).
    short8 vf0[4], vf1[4];
#pragma unroll
    for (int kc = 0; kc < 4; kc++) {
      const int kbase = keyoff + kc * 32 + lh * 8;  // contiguous 8 keys
      vf0[kc] = *(const short8*)&Vg[(size_t)lr * NA + kbase];
      vf1[kc] = *(const short8*)&Vg[(size_t)(16 + lr) * NA + kbase];
    }
    // pin: V loads may not sink below this point
    __builtin_amdgcn_sched_barrier(0);

    // (2) S^T = K * Q^T from the preloaded K buffer
    floatx4 s[8];
#pragma unroll
    for (int kt = 0; kt < 8; kt++) s[kt] = z;
#pragma unroll
    for (int kt = 0; kt < 8; kt++) s[kt] = mfma16(kf[kt], qf, s[kt]);

    // (3) prefetch K(tile+1) — latency hides under softmax + PV
    if (tile < 3) {
      const int nko = keyoff + 128;
#pragma unroll
      for (int kt = 0; kt < 8; kt++)
        kf[kt] = *(const short8*)&Kg[(size_t)(nko + kt * 16 + lr) * DH + lh * 8];
    }
    // pin: QK + K-prefetch stay above; softmax stays below
    __builtin_amdgcn_sched_barrier(0);

    // (4) bias + softmax (V and K-next in flight underneath)
    float pmax = -3.0e38f;
#pragma unroll
    for (int kt = 0; kt < 8; kt++) {
      float4 av = *(const float4*)&adj_lds[lr][keyoff + kt * 16 + lh * 4];
      float v0 = s[kt][0] * INV_TP + av.x;
      float v1 = s[kt][1] * INV_TP + av.y;
      float v2 = s[kt][2] * INV_TP + av.z;
      float v3 = s[kt][3] * INV_TP + av.w;
      s[kt][0] = v0; s[kt][1] = v1; s[kt][2] = v2; s[kt][3] = v3;
      pmax = fmaxf(pmax, fmaxf(fmaxf(v0, v1), fmaxf(v2, v3)));
    }
    // row q lives in lanes {lr, lr+16, lr+32, lr+48}
    pmax = fmaxf(pmax, __shfl_xor(pmax, 16));
    pmax = fmaxf(pmax, __shfl_xor(pmax, 32));

    const float mnew = fmaxf(m_run, pmax);
    if (tile) {  // tile 0: o/l are zero, skip rescale
      const float corr = __expf(m_run - mnew);
      l_run *= corr;
#pragma unroll
      for (int r = 0; r < 4; r++) {
        float c = __shfl(corr, lh * 4 + r, 64);
        o0[r] *= c;
        o1[r] *= c;
      }
    }
    m_run = mnew;

    float sum = 0.f;
#pragma unroll
    for (int kt = 0; kt < 8; kt++) {
      float e0 = __expf(s[kt][0] - mnew);
      float e1 = __expf(s[kt][1] - mnew);
      float e2 = __expf(s[kt][2] - mnew);
      float e3 = __expf(s[kt][3] - mnew);
      s[kt][0] = e0; s[kt][1] = e1; s[kt][2] = e2; s[kt][3] = e3;
      sum += (e0 + e1) + (e2 + e3);
    }
    sum += __shfl_xor(sum, 16);
    sum += __shfl_xor(sum, 32);
    l_run += sum;

    // (5) PV. A-frag slot j <-> key kc*32 + old(lh*4+j | 16+lh*4+j-4); V stored
    // permuted so B-frag slot j is contiguous position lh*8+j. f2bf packing.
#pragma unroll
    for (int kc = 0; kc < 4; kc++) {
      union { short8 s8; unsigned int u[4]; } aa;
      aa.u[0] = (unsigned int)f2bf(s[2 * kc][0]) |
                ((unsigned int)f2bf(s[2 * kc][1]) << 16);
      aa.u[1] = (unsigned int)f2bf(s[2 * kc][2]) |
                ((unsigned int)f2bf(s[2 * kc][3]) << 16);
      aa.u[2] = (unsigned int)f2bf(s[2 * kc + 1][0]) |
                ((unsigned int)f2bf(s[2 * kc + 1][1]) << 16);
      aa.u[3] = (unsigned int)f2bf(s[2 * kc + 1][2]) |
                ((unsigned int)f2bf(s[2 * kc + 1][3]) << 16);
      o0 = mfma16(aa.s8, vf0[kc], o0);
      o1 = mfma16(aa.s8, vf1[kc], o1);
    }
  }

  const float inv = 1.0f / l_run;  // for q = q0 + lr
#pragma unroll
  for (int r = 0; r < 4; r++) {
    float iv = __shfl(inv, lh * 4 + r, 64);  // row q0+lh*4+r's normalizer
    size_t idx = ((size_t)b * NA + (q0 + lh * 4 + r)) * HID + h * DH + lr;
    out[idx] = o0[r] * iv + X[idx];
    out[idx + 16] = o1[r] * iv + X[idx + 16];
  }
}

extern "C" void kernel_launch(void* const* d_in, const int* in_sizes, int n_in,
                              void* d_out, int out_size, void* d_ws, size_t ws_size,
                              hipStream_t stream) {
  const float* x = (const float*)d_in[0];
  const void* mask = d_in[1];
  const float* adj = (const float*)d_in[2];
  const float* Wq = (const float*)d_in[3];
  const float* Wk = (const float*)d_in[4];
  const float* Wv = (const float*)d_in[5];
  float* out = (float*)d_out;

  char* ws = (char*)d_ws;
  const size_t MB = 1048576;
  const size_t NEED = 512 * 1024 + 3 * 4 * MB;  // Wbf + QKV = 12.5MB

  unsigned short *Qw, *Kw, *Vw;
  if (ws_size >= NEED) {
    unsigned short* Wbf = (unsigned short*)ws;                   // 384 KB (+pad)
    Qw = (unsigned short*)(ws + 512 * 1024);                     // 4 MB
    Kw = (unsigned short*)(ws + 512 * 1024 + 4 * MB);            // 4 MB
    Vw = (unsigned short*)(ws + 512 * 1024 + 8 * MB);            // 4 MB (transposed+permuted)
    cvt_w<<<64, 256, 0, stream>>>(Wq, Wk, Wv, Wbf);
    qkv_fused<<<dim3(256, 3), 256, 0, stream>>>(x, Wbf, Qw);
  } else {
    Qw = (unsigned short*)(ws + 4096);
    Kw = (unsigned short*)(ws + 4096 + 4 * MB);
    Vw = (unsigned short*)(ws + 4096 + 8 * MB);
    qkv_proj<<<dim3(256, 3), 256, 0, stream>>>(x, Wq, Wk, Wv, Qw);
  }
  attn_fused<<<dim3(32, NB), 512, 0, stream>>>(
      Qw, Kw, Vw, x, (const unsigned char*)mask, (const int*)mask, adj, out);
}

// Round 25
// 53.533 us; speedup vs baseline: 1.3943x; 1.0906x over previous
//
#include <hip/hip_runtime.h>
#include <hip/hip_bf16.h>

// MultiHeadAttention: x(16,512,256) f32; mask(1,16,512,512) bool; adj(1,16,512,512) f32;
// Wq/Wk/Wv (256,256) f32.  out = softmax(QK^T/sqrt(64) + adj, mask) @ V + x, f32.
// R24: V group-tiled layout [b][h][g][d][w] (g=key-group of 32, w=permuted pos).
// attn V-loads become single 1KB contiguous segments/instr (were 16 scattered
// 64B segments) -> V requests /8. Same values bit-for-bit (only storage moved);
// writer epilogues updated to match. Everything else = R22 (58.4us validated).

#define NB 16
#define NA 512
#define HID 256
#define NHEAD 8
#define DH 32
#define INV_TP 0.125f  // 1/sqrt(2*32)
#define ADJ_LD 520     // 512 cols + 8 pad (f32)
#define XT_LD 264      // 256 cols + 8 pad (bf16), row stride 528B (16B-aligned)

typedef __attribute__((ext_vector_type(8))) short short8;   // 8 bf16 MFMA frag
typedef __attribute__((ext_vector_type(4))) float floatx4;  // MFMA acc

__device__ __forceinline__ unsigned short f2bf(float f) {
  unsigned int u = __builtin_bit_cast(unsigned int, f);
  u += 0x7fffu + ((u >> 16) & 1u);  // round-to-nearest-even
  return (unsigned short)(u >> 16);
}

__device__ __forceinline__ floatx4 mfma16(short8 a, short8 b, floatx4 c) {
  return __builtin_amdgcn_mfma_f32_16x16x32_bf16(a, b, c, 0, 0, 0);
}

__device__ __forceinline__ short8 ld8f32_bf16(const float* __restrict__ p) {
  float4 a = *(const float4*)p;
  float4 b = *(const float4*)(p + 4);
  short8 r;
  r[0] = (short)f2bf(a.x); r[1] = (short)f2bf(a.y);
  r[2] = (short)f2bf(a.z); r[3] = (short)f2bf(a.w);
  r[4] = (short)f2bf(b.x); r[5] = (short)f2bf(b.y);
  r[6] = (short)f2bf(b.z); r[7] = (short)f2bf(b.w);
  return r;
}

// V key permutation within each 32-key group: old g -> new position.
// Makes PV B-frag keys contiguous per (kc, lh): new = lh*8 + (0..7).
__device__ __forceinline__ int vperm32(int g) {
  return (((g & 15) >> 2) << 3) + (g & 3) + (((g >> 4) & 1) << 2);
}

// W-only f32->bf16 (3 x 64K elems). ~1us.
__global__ __launch_bounds__(256) void cvt_w(
    const float* __restrict__ Wq, const float* __restrict__ Wk,
    const float* __restrict__ Wv, unsigned short* __restrict__ Wbf) {
  const int tid = blockIdx.x * blockDim.x + threadIdx.x;
  const int stride = gridDim.x * blockDim.x;
  for (int i = tid; i < (HID * HID) / 4; i += stride) {
    float4 v = ((const float4*)Wq)[i];
    ushort4 w;
    w.x = f2bf(v.x); w.y = f2bf(v.y); w.z = f2bf(v.z); w.w = f2bf(v.w);
    ((ushort4*)Wbf)[i] = w;
    v = ((const float4*)Wk)[i];
    w.x = f2bf(v.x); w.y = f2bf(v.y); w.z = f2bf(v.z); w.w = f2bf(v.w);
    ((ushort4*)(Wbf + HID * HID))[i] = w;
    v = ((const float4*)Wv)[i];
    w.x = f2bf(v.x); w.y = f2bf(v.y); w.z = f2bf(v.z); w.w = f2bf(v.w);
    ((ushort4*)(Wbf + 2 * HID * HID))[i] = w;
  }
}

// Fused projection: convert 32 X-rows to LDS once, GEMM vs Wbf, coalesced
// epilogue. grid (256, 3); block 256 (4 waves x 64 cols).
// Q,K stored [b][h][n][d]; V stored GROUP-TILED [b][h][g][d][w], g=n>>5,
// w=vperm32(n&31): attn reads are 1KB-contiguous per (g, d-half).
__global__ __launch_bounds__(256) void qkv_fused(
    const float* __restrict__ X, const unsigned short* __restrict__ Wbf,
    unsigned short* __restrict__ Y) {
  __shared__ __align__(16) unsigned short xt[32][XT_LD];  // 16,896 B (reused)
  const unsigned short* W = Wbf + (size_t)blockIdx.y * (HID * HID);
  unsigned short* Yo = Y + (size_t)blockIdx.y * (NB * NHEAD * NA * DH);
  const int t = threadIdx.x;
  const int wave = t >> 6, lane = t & 63;
  const int lr = lane & 15, lh = lane >> 4;
  const int m0 = blockIdx.x * 32;
  const int cb = wave * 64;

  // Phase 1: convert own X tile (32 rows x 256) into LDS.
  {
    const int r = t >> 3, c0 = (t & 7) * 32;
    const float* xrow = X + (size_t)(m0 + r) * HID + c0;
#pragma unroll
    for (int j = 0; j < 8; j++) {
      float4 v = ((const float4*)xrow)[j];
      ushort4 w;
      w.x = f2bf(v.x); w.y = f2bf(v.y); w.z = f2bf(v.z); w.w = f2bf(v.w);
      *(ushort4*)&xt[r][c0 + j * 4] = w;
    }
  }
  __syncthreads();

  // Phase 2: GEMM. A from LDS, B from Wbf (L2-resident).
  const floatx4 z = {0.f, 0.f, 0.f, 0.f};
  floatx4 acc[2][4];
#pragma unroll
  for (int i = 0; i < 2; i++)
#pragma unroll
    for (int j = 0; j < 4; j++) acc[i][j] = z;

  for (int kb = 0; kb < HID; kb += 32) {
    short8 a[2], bw[4];
#pragma unroll
    for (int rt = 0; rt < 2; rt++)
      a[rt] = *(const short8*)&xt[rt * 16 + lr][kb + lh * 8];
#pragma unroll
    for (int ci = 0; ci < 4; ci++)
      bw[ci] = *(const short8*)&W[(size_t)(cb + ci * 16 + lr) * HID + kb + lh * 8];
#pragma unroll
    for (int rt = 0; rt < 2; rt++)
#pragma unroll
      for (int ci = 0; ci < 4; ci++)
        acc[rt][ci] = mfma16(a[rt], bw[ci], acc[rt][ci]);
  }
  __syncthreads();  // all LDS A-reads done; xt reusable

  if (blockIdx.y == 2) {
    // V: group-tiled stores: [b][h][g][d][w], ushort4 at w0=vperm32(n0&31).
#pragma unroll
    for (int rt = 0; rt < 2; rt++)
#pragma unroll
      for (int ci = 0; ci < 4; ci++) {
        int m = m0 + rt * 16 + lh * 4;       // keys m..m+3 (same batch: 32|512)
        int c = cb + ci * 16 + lr;
        int bb = m >> 9, n0 = m & 511, hh = c >> 5, dd = c & 31;
        int g = n0 >> 5;
        int w0 = vperm32(n0 & 31);           // 4-aligned, stays contiguous
        ushort4 w;
        w.x = f2bf(acc[rt][ci][0]);
        w.y = f2bf(acc[rt][ci][1]);
        w.z = f2bf(acc[rt][ci][2]);
        w.w = f2bf(acc[rt][ci][3]);
        *(ushort4*)&Yo[(size_t)(((bb * NHEAD + hh) * 16 + g) * 32 + dd) * 32 + w0] = w;
      }
    __syncthreads();  // match Q/K path barrier
  } else {
    // Q/K: stage tile in LDS (D-layout scatter, cheap 2B LDS writes), then
    // 4 x 16B coalesced global stores per thread.
#pragma unroll
    for (int rt = 0; rt < 2; rt++)
#pragma unroll
      for (int ci = 0; ci < 4; ci++)
#pragma unroll
        for (int r = 0; r < 4; r++)
          xt[rt * 16 + lh * 4 + r][cb + ci * 16 + lr] = f2bf(acc[rt][ci][r]);
    __syncthreads();
#pragma unroll
    for (int j = 0; j < 4; j++) {
      const int chunk = t + j * 256;        // 1024 chunks of 8 cols
      const int row = chunk >> 5;           // 0..31
      const int c0 = (chunk & 31) * 8;      // 0..248, within one head
      const int n = m0 + row;
      const int bb = n >> 9, nn = n & 511, hh = c0 >> 5, dd = c0 & 31;
      *(uint4*)&Yo[((size_t)(bb * NHEAD + hh) * NA + nn) * DH + dd] =
          *(const uint4*)&xt[row][c0];
    }
  }
}

// Fallback projection (f32 direct, inline cvt). Used only if ws too small.
__global__ __launch_bounds__(256) void qkv_proj(
    const float* __restrict__ X, const float* __restrict__ Wq,
    const float* __restrict__ Wk, const float* __restrict__ Wv,
    unsigned short* __restrict__ Y) {
  const float* W = (blockIdx.y == 0) ? Wq : (blockIdx.y == 1) ? Wk : Wv;
  unsigned short* Yo = Y + (size_t)blockIdx.y * (NB * NHEAD * NA * DH);
  const int wave = threadIdx.x >> 6, lane = threadIdx.x & 63;
  const int lr = lane & 15, lh = lane >> 4;
  const int m0 = blockIdx.x * 32;
  const int cb = wave * 64;
  const floatx4 z = {0.f, 0.f, 0.f, 0.f};
  floatx4 acc[2][4];
#pragma unroll
  for (int i = 0; i < 2; i++)
#pragma unroll
    for (int j = 0; j < 4; j++) acc[i][j] = z;

  for (int kb = 0; kb < HID; kb += 32) {
    short8 a[2], bw[4];
#pragma unroll
    for (int rt = 0; rt < 2; rt++)
      a[rt] = ld8f32_bf16(X + (size_t)(m0 + rt * 16 + lr) * HID + kb + lh * 8);
#pragma unroll
    for (int ci = 0; ci < 4; ci++)
      bw[ci] = ld8f32_bf16(W + (size_t)(cb + ci * 16 + lr) * HID + kb + lh * 8);
#pragma unroll
    for (int rt = 0; rt < 2; rt++)
#pragma unroll
      for (int ci = 0; ci < 4; ci++)
        acc[rt][ci] = mfma16(a[rt], bw[ci], acc[rt][ci]);
  }
  if (blockIdx.y == 2) {
#pragma unroll
    for (int rt = 0; rt < 2; rt++)
#pragma unroll
      for (int ci = 0; ci < 4; ci++) {
        int m = m0 + rt * 16 + lh * 4;
        int c = cb + ci * 16 + lr;
        int bb = m >> 9, n0 = m & 511, hh = c >> 5, dd = c & 31;
        int g = n0 >> 5;
        int w0 = vperm32(n0 & 31);
        ushort4 w;
        w.x = f2bf(acc[rt][ci][0]);
        w.y = f2bf(acc[rt][ci][1]);
        w.z = f2bf(acc[rt][ci][2]);
        w.w = f2bf(acc[rt][ci][3]);
        *(ushort4*)&Yo[(size_t)(((bb * NHEAD + hh) * 16 + g) * 32 + dd) * 32 + w0] = w;
      }
  } else {
#pragma unroll
    for (int rt = 0; rt < 2; rt++)
#pragma unroll
      for (int ci = 0; ci < 4; ci++)
#pragma unroll
        for (int r = 0; r < 4; r++) {
          int m = m0 + rt * 16 + lh * 4 + r;
          int c = cb + ci * 16 + lr;
          int bb = m >> 9, n = m & 511, hh = c >> 5, dd = c & 31;
          Yo[((size_t)(bb * NHEAD + hh) * NA + n) * DH + dd] = f2bf(acc[rt][ci][r]);
        }
  }
}

// grid: (32 q-blocks of 16 rows, 16 batch) = 512 blocks, 512 thr.
// Wave h = head h, all 512 keys (4 tiles of 128, online softmax).
// Bias staged once (1 barrier). V loads: 1KB-contiguous per (group, d-half).
__global__ __launch_bounds__(512, 2) void attn_fused(
    const unsigned short* __restrict__ Qw, const unsigned short* __restrict__ Kw,
    const unsigned short* __restrict__ Vtg, const float* __restrict__ X,
    const unsigned char* __restrict__ maskB, const int* __restrict__ maskI,
    const float* __restrict__ adj, float* __restrict__ out) {
  __shared__ float adj_lds[16][ADJ_LD];  // 33,280 B
  const int qb = blockIdx.x, b = blockIdx.y;
  const int t = threadIdx.x;
  const int h = t >> 6, lane = t & 63, lr = lane & 15, lh = lane >> 4;
  const int q0 = qb * 16;
  const size_t bh = (size_t)(b * NHEAD + h) * NA * DH;
  const unsigned short* Kg = Kw + bh;
  const unsigned short* Vg = Vtg + bh;  // [g][d][w]: g*1024 + d*32 + w

  // Q fragment + K(0) fragments issued first (independent of staging)
  short8 qf = *(const short8*)&Qw[bh + (size_t)(q0 + lr) * DH + lh * 8];
  short8 kf[8];
#pragma unroll
  for (int kt = 0; kt < 8; kt++)
    kf[kt] = *(const short8*)&Kg[(size_t)(kt * 16 + lr) * DH + lh * 8];

  // mask dtype detect (wave-level over first 512 words; wave-uniform result).
  const unsigned int* mu = (const unsigned int*)maskB;
  unsigned int cnt = 0;
#pragma unroll
  for (int j = 0; j < 8; j++) cnt += (mu[lane + j * 64] != 0u) ? 1u : 0u;
#pragma unroll
  for (int off = 32; off > 0; off >>= 1) cnt += __shfl_xor(cnt, off);
  const bool mBytes = (cnt > 368u);

  // stage the full 16x512 bias block (mask merged: masked -> -1e30).
#pragma unroll
  for (int j = 0; j < 4; j++) {
    const int slot = t + j * 512;
    const int srow = slot >> 7;            // 128 float4 per row
    const int sc4 = (slot & 127) * 4;
    const size_t soff = ((size_t)b * NA + q0 + srow) * NA + sc4;
    float4 av = *(const float4*)&adj[soff];
    if (mBytes) {
      uchar4 mb = *(const uchar4*)&maskB[soff];
      if (mb.x) av.x = -1e30f;
      if (mb.y) av.y = -1e30f;
      if (mb.z) av.z = -1e30f;
      if (mb.w) av.w = -1e30f;
    } else {
      int4 mi = *(const int4*)&maskI[soff];
      if (mi.x) av.x = -1e30f;
      if (mi.y) av.y = -1e30f;
      if (mi.z) av.z = -1e30f;
      if (mi.w) av.w = -1e30f;
    }
    *(float4*)&adj_lds[srow][sc4] = av;
  }
  __syncthreads();  // the ONLY barrier

  const floatx4 z = {0.f, 0.f, 0.f, 0.f};
  float m_run = -3.0e38f, l_run = 0.f;  // state for q = q0 + lr (S^T layout)
  floatx4 o0 = z, o1 = z;               // rows q0 + lh*4 + r (C/D layout)

#pragma unroll 1
  for (int tile = 0; tile < 4; ++tile) {
    const int keyoff = tile * 128;

    // (1) V(tile) loads first: per group g, two 1KB-contiguous wave-loads.
    short8 vf0[4], vf1[4];
#pragma unroll
    for (int kc = 0; kc < 4; kc++) {
      const int g = tile * 4 + kc;
      vf0[kc] = *(const short8*)&Vg[(size_t)g * 1024 + lr * 32 + lh * 8];
      vf1[kc] = *(const short8*)&Vg[(size_t)g * 1024 + (16 + lr) * 32 + lh * 8];
    }
    // pin: V loads may not sink below this point
    __builtin_amdgcn_sched_barrier(0);

    // (2) S^T = K * Q^T from the preloaded K buffer
    floatx4 s[8];
#pragma unroll
    for (int kt = 0; kt < 8; kt++) s[kt] = z;
#pragma unroll
    for (int kt = 0; kt < 8; kt++) s[kt] = mfma16(kf[kt], qf, s[kt]);

    // (3) prefetch K(tile+1) — latency hides under softmax + PV
    if (tile < 3) {
      const int nko = keyoff + 128;
#pragma unroll
      for (int kt = 0; kt < 8; kt++)
        kf[kt] = *(const short8*)&Kg[(size_t)(nko + kt * 16 + lr) * DH + lh * 8];
    }
    // pin: QK + K-prefetch stay above; softmax stays below
    __builtin_amdgcn_sched_barrier(0);

    // (4) bias + softmax (V and K-next in flight underneath)
    float pmax = -3.0e38f;
#pragma unroll
    for (int kt = 0; kt < 8; kt++) {
      float4 av = *(const float4*)&adj_lds[lr][keyoff + kt * 16 + lh * 4];
      float v0 = s[kt][0] * INV_TP + av.x;
      float v1 = s[kt][1] * INV_TP + av.y;
      float v2 = s[kt][2] * INV_TP + av.z;
      float v3 = s[kt][3] * INV_TP + av.w;
      s[kt][0] = v0; s[kt][1] = v1; s[kt][2] = v2; s[kt][3] = v3;
      pmax = fmaxf(pmax, fmaxf(fmaxf(v0, v1), fmaxf(v2, v3)));
    }
    // row q lives in lanes {lr, lr+16, lr+32, lr+48}
    pmax = fmaxf(pmax, __shfl_xor(pmax, 16));
    pmax = fmaxf(pmax, __shfl_xor(pmax, 32));

    const float mnew = fmaxf(m_run, pmax);
    if (tile) {  // tile 0: o/l are zero, skip rescale
      const float corr = __expf(m_run - mnew);
      l_run *= corr;
#pragma unroll
      for (int r = 0; r < 4; r++) {
        float c = __shfl(corr, lh * 4 + r, 64);
        o0[r] *= c;
        o1[r] *= c;
      }
    }
    m_run = mnew;

    float sum = 0.f;
#pragma unroll
    for (int kt = 0; kt < 8; kt++) {
      float e0 = __expf(s[kt][0] - mnew);
      float e1 = __expf(s[kt][1] - mnew);
      float e2 = __expf(s[kt][2] - mnew);
      float e3 = __expf(s[kt][3] - mnew);
      s[kt][0] = e0; s[kt][1] = e1; s[kt][2] = e2; s[kt][3] = e3;
      sum += (e0 + e1) + (e2 + e3);
    }
    sum += __shfl_xor(sum, 16);
    sum += __shfl_xor(sum, 32);
    l_run += sum;

    // (5) PV. A-frag slot j <-> key kc*32 + old(lh*4+j | 16+lh*4+j-4); V group-
    // tiled so B-frag slot j sits at position lh*8+j of group g. f2bf packing.
#pragma unroll
    for (int kc = 0; kc < 4; kc++) {
      union { short8 s8; unsigned int u[4]; } aa;
      aa.u[0] = (unsigned int)f2bf(s[2 * kc][0]) |
                ((unsigned int)f2bf(s[2 * kc][1]) << 16);
      aa.u[1] = (unsigned int)f2bf(s[2 * kc][2]) |
                ((unsigned int)f2bf(s[2 * kc][3]) << 16);
      aa.u[2] = (unsigned int)f2bf(s[2 * kc + 1][0]) |
                ((unsigned int)f2bf(s[2 * kc + 1][1]) << 16);
      aa.u[3] = (unsigned int)f2bf(s[2 * kc + 1][2]) |
                ((unsigned int)f2bf(s[2 * kc + 1][3]) << 16);
      o0 = mfma16(aa.s8, vf0[kc], o0);
      o1 = mfma16(aa.s8, vf1[kc], o1);
    }
  }

  const float inv = 1.0f / l_run;  // for q = q0 + lr
#pragma unroll
  for (int r = 0; r < 4; r++) {
    float iv = __shfl(inv, lh * 4 + r, 64);  // row q0+lh*4+r's normalizer
    size_t idx = ((size_t)b * NA + (q0 + lh * 4 + r)) * HID + h * DH + lr;
    out[idx] = o0[r] * iv + X[idx];
    out[idx + 16] = o1[r] * iv + X[idx + 16];
  }
}

extern "C" void kernel_launch(void* const* d_in, const int* in_sizes, int n_in,
                              void* d_out, int out_size, void* d_ws, size_t ws_size,
                              hipStream_t stream) {
  const float* x = (const float*)d_in[0];
  const void* mask = d_in[1];
  const float* adj = (const float*)d_in[2];
  const float* Wq = (const float*)d_in[3];
  const float* Wk = (const float*)d_in[4];
  const float* Wv = (const float*)d_in[5];
  float* out = (float*)d_out;

  char* ws = (char*)d_ws;
  const size_t MB = 1048576;
  const size_t NEED = 512 * 1024 + 3 * 4 * MB;  // Wbf + QKV = 12.5MB

  unsigned short *Qw, *Kw, *Vw;
  if (ws_size >= NEED) {
    unsigned short* Wbf = (unsigned short*)ws;                   // 384 KB (+pad)
    Qw = (unsigned short*)(ws + 512 * 1024);                     // 4 MB
    Kw = (unsigned short*)(ws + 512 * 1024 + 4 * MB);            // 4 MB
    Vw = (unsigned short*)(ws + 512 * 1024 + 8 * MB);            // 4 MB (group-tiled)
    cvt_w<<<64, 256, 0, stream>>>(Wq, Wk, Wv, Wbf);
    qkv_fused<<<dim3(256, 3), 256, 0, stream>>>(x, Wbf, Qw);
  } else {
    Qw = (unsigned short*)(ws + 4096);
    Kw = (unsigned short*)(ws + 4096 + 4 * MB);
    Vw = (unsigned short*)(ws + 4096 + 8 * MB);
    qkv_proj<<<dim3(256, 3), 256, 0, stream>>>(x, Wq, Wk, Wv, Qw);
  }
  attn_fused<<<dim3(32, NB), 512, 0, stream>>>(
      Qw, Kw, Vw, x, (const unsigned char*)mask, (const int*)mask, adj, out);
}